// Round 1
// baseline (514.623 us; speedup 1.0000x reference)
//
#include <hip/hip_runtime.h>
#include <hip/hip_bf16.h>

typedef __attribute__((ext_vector_type(4))) float f32x4;
typedef __attribute__((ext_vector_type(8))) short bf16x8;
typedef __attribute__((ext_vector_type(4))) short s16x4;

#define C_DIM 512
#define N_PIX 2304
#define N_BATCH 8
#define ATT_SCALE 0.04419417382415922f

// ---------------------------------------------------------------------------
// Generic block-tiled MFMA GEMM:  D[i,j] = scale * sum_k a(i,k)*b(j,k) + bias
//   TRANS_A=0: A bf16 [I x lda], a(i,k)=A[i*lda+k]
//   TRANS_A=1: A fp32 [K x lda], a(i,k)=A[k*lda+i]  (transpose+cast on stage)
//   (same for B with j)
//   OUT_BF16: 1 -> bf16 store, 0 -> fp32 store
//   BIAS_MODE: 0 none, 1 per-i, 2 per-j
// Tiles: 128x128 per block, BK=64, 256 threads (4 waves), each wave 64x64 via
// 4x4 grid of 16x16x32 bf16 MFMAs. Batch via blockIdx.z + element strides.
// Requires I%128==0, J%128==0, K%64==0 (true for all shapes here).
// ---------------------------------------------------------------------------
template<int TRANS_A, int TRANS_B, int OUT_BF16, int BIAS_MODE>
__global__ __launch_bounds__(256)
void gemm_bt(const void* __restrict__ Ap, const void* __restrict__ Bp,
             void* __restrict__ Dp, const float* __restrict__ bias,
             float scale, int I, int J, int K,
             int lda, int ldb, int ldd,
             long sA, long sB, long sD)
{
    constexpr int BI = 128, BJ = 128, BK = 64, LS = 72; // LS: +8 bf16 pad, keeps 16B align
    __shared__ __hip_bfloat16 As[BI * LS];
    __shared__ __hip_bfloat16 Bs[BJ * LS];

    const int tid  = threadIdx.x;
    const int lane = tid & 63;
    const int wave = tid >> 6;
    const int i0 = blockIdx.x * BI;
    const int j0 = blockIdx.y * BJ;
    const size_t bz = blockIdx.z;

    const __hip_bfloat16* A16 = (const __hip_bfloat16*)Ap + (TRANS_A == 0 ? bz * (size_t)sA : 0);
    const float*          A32 = (const float*)Ap          + (TRANS_A == 1 ? bz * (size_t)sA : 0);
    const __hip_bfloat16* B16 = (const __hip_bfloat16*)Bp + (TRANS_B == 0 ? bz * (size_t)sB : 0);
    const float*          B32 = (const float*)Bp          + (TRANS_B == 1 ? bz * (size_t)sB : 0);
    __hip_bfloat16* D16 = (__hip_bfloat16*)Dp + bz * (size_t)sD;
    float*          D32 = (float*)Dp          + bz * (size_t)sD;

    const int fr = lane & 15;          // fragment row (A) / col (B)
    const int fq = (lane >> 4) * 8;    // fragment k offset within 32
    const int wi = (wave >> 1) * 64;
    const int wj = (wave & 1) * 64;

    f32x4 acc[4][4];
#pragma unroll
    for (int a = 0; a < 4; ++a)
#pragma unroll
        for (int b = 0; b < 4; ++b)
            acc[a][b] = (f32x4){0.f, 0.f, 0.f, 0.f};

    for (int k0 = 0; k0 < K; k0 += BK) {
        // ---- stage A tile [128 i][64 k] ----
        if (TRANS_A == 0) {
#pragma unroll
            for (int s = 0; s < 4; ++s) {
                int ch  = tid + s * 256;       // 1024 chunks of 8 bf16
                int row = ch >> 3;
                int kc  = (ch & 7) << 3;
                *(int4*)(&As[row * LS + kc]) =
                    *(const int4*)(&A16[(size_t)(i0 + row) * lda + k0 + kc]);
            }
        } else {
            int il  = tid & 127;
            int kb0 = (tid >> 7) * 8;
#pragma unroll
            for (int s = 0; s < 4; ++s) {
                int kb = kb0 + s * 16;         // covers all 8 k-chunks over (kb0,s)
                union { __hip_bfloat16 h[8]; int4 v; } t;
#pragma unroll
                for (int u = 0; u < 8; ++u)
                    t.h[u] = __float2bfloat16(A32[(size_t)(k0 + kb + u) * lda + i0 + il]);
                *(int4*)(&As[il * LS + kb]) = t.v;
            }
        }
        // ---- stage B tile [128 j][64 k] ----
        if (TRANS_B == 0) {
#pragma unroll
            for (int s = 0; s < 4; ++s) {
                int ch  = tid + s * 256;
                int row = ch >> 3;
                int kc  = (ch & 7) << 3;
                *(int4*)(&Bs[row * LS + kc]) =
                    *(const int4*)(&B16[(size_t)(j0 + row) * ldb + k0 + kc]);
            }
        } else {
            int jl  = tid & 127;
            int kb0 = (tid >> 7) * 8;
#pragma unroll
            for (int s = 0; s < 4; ++s) {
                int kb = kb0 + s * 16;
                union { __hip_bfloat16 h[8]; int4 v; } t;
#pragma unroll
                for (int u = 0; u < 8; ++u)
                    t.h[u] = __float2bfloat16(B32[(size_t)(k0 + kb + u) * ldb + j0 + jl]);
                *(int4*)(&Bs[jl * LS + kb]) = t.v;
            }
        }
        __syncthreads();

        // ---- MFMA inner loop ----
#pragma unroll
        for (int kk = 0; kk < BK; kk += 32) {
            bf16x8 af[4], bfr[4];
#pragma unroll
            for (int t = 0; t < 4; ++t) {
                af[t]  = *(const bf16x8*)(&As[(wi + t * 16 + fr) * LS + kk + fq]);
                bfr[t] = *(const bf16x8*)(&Bs[(wj + t * 16 + fr) * LS + kk + fq]);
            }
#pragma unroll
            for (int a = 0; a < 4; ++a)
#pragma unroll
                for (int b = 0; b < 4; ++b)
                    acc[a][b] = __builtin_amdgcn_mfma_f32_16x16x32_bf16(
                        af[a], bfr[b], acc[a][b], 0, 0, 0);
        }
        __syncthreads();
    }

    // ---- epilogue: D[row=(lane>>4)*4+r][col=lane&15] per 16x16 tile ----
    const int orow = (lane >> 4) * 4;
#pragma unroll
    for (int a = 0; a < 4; ++a) {
        int ib = i0 + wi + a * 16 + orow;
#pragma unroll
        for (int b = 0; b < 4; ++b) {
            int j = j0 + wj + b * 16 + fr;
            float bj = (BIAS_MODE == 2) ? bias[j] : 0.f;
#pragma unroll
            for (int r = 0; r < 4; ++r) {
                int i = ib + r;
                float v = acc[a][b][r] * scale;
                if (BIAS_MODE == 1) v += bias[i];
                if (BIAS_MODE == 2) v += bj;
                if (OUT_BF16)
                    D16[(size_t)i * ldd + j] = __float2bfloat16(v);
                else
                    D32[(size_t)i * ldd + j] = v;
            }
        }
    }
}

// ---------------------------------------------------------------------------
// Row softmax: S fp32 [rows x 2304] -> P bf16. One block (256 thr) per row.
// ---------------------------------------------------------------------------
__global__ __launch_bounds__(256)
void softmax_rows(const float* __restrict__ S, __hip_bfloat16* __restrict__ P)
{
    const int row = blockIdx.x;
    const float* s = S + (size_t)row * N_PIX;
    __hip_bfloat16* p = P + (size_t)row * N_PIX;
    const int tid = threadIdx.x;

    float v[9];
    float vmax = -3.4e38f;
#pragma unroll
    for (int t = 0; t < 9; ++t) {
        v[t] = s[tid + t * 256];
        vmax = fmaxf(vmax, v[t]);
    }
    __shared__ float red[4];
    for (int off = 32; off > 0; off >>= 1)
        vmax = fmaxf(vmax, __shfl_down(vmax, off));
    if ((tid & 63) == 0) red[tid >> 6] = vmax;
    __syncthreads();
    vmax = fmaxf(fmaxf(red[0], red[1]), fmaxf(red[2], red[3]));

    float sum = 0.f;
#pragma unroll
    for (int t = 0; t < 9; ++t) { v[t] = __expf(v[t] - vmax); sum += v[t]; }
    for (int off = 32; off > 0; off >>= 1)
        sum += __shfl_down(sum, off);
    __syncthreads();
    if ((tid & 63) == 0) red[tid >> 6] = sum;
    __syncthreads();
    float inv = 1.f / (red[0] + red[1] + red[2] + red[3]);
#pragma unroll
    for (int t = 0; t < 9; ++t)
        p[tid + t * 256] = __float2bfloat16(v[t] * inv);
}

// ---------------------------------------------------------------------------
__global__ __launch_bounds__(256)
void cast_f32_to_bf16(const float* __restrict__ src, __hip_bfloat16* __restrict__ dst, int n)
{
    int i = (blockIdx.x * 256 + threadIdx.x) * 4;
    if (i + 3 < n) {
        float4 f = *(const float4*)(src + i);
        union { __hip_bfloat16 h[4]; s16x4 v; } t;
        t.h[0] = __float2bfloat16(f.x);
        t.h[1] = __float2bfloat16(f.y);
        t.h[2] = __float2bfloat16(f.z);
        t.h[3] = __float2bfloat16(f.w);
        *(s16x4*)(dst + i) = t.v;
    }
}

// ---------------------------------------------------------------------------
extern "C" void kernel_launch(void* const* d_in, const int* in_sizes, int n_in,
                              void* d_out, int out_size, void* d_ws, size_t ws_size,
                              hipStream_t stream)
{
    const float* locx = (const float*)d_in[0];
    const float* glox = (const float*)d_in[1];
    const float* Wq = (const float*)d_in[2];
    const float* bq = (const float*)d_in[3];
    const float* Wk = (const float*)d_in[4];
    const float* bk = (const float*)d_in[5];
    const float* Wv = (const float*)d_in[6];
    const float* bv = (const float*)d_in[7];
    const float* Wo = (const float*)d_in[8];
    const float* bo = (const float*)d_in[9];
    float* out = (float*)d_out;

    const int C = C_DIM, N = N_PIX, B = N_BATCH;
    const size_t WB  = (size_t)C * C * 2;      // bf16 weight bytes
    const size_t szQ = (size_t)N * C * 2;      // per-batch projection (bf16)
    const size_t szS = (size_t)N * N * 4;      // per-batch scores (fp32)
    const size_t szP = (size_t)N * N * 2;      // per-batch probs (bf16)

    const size_t need2 = 4 * WB + 4 * 8 * szQ + szS + 8 * szP; // ~184 MB
    const size_t need1 = 4 * WB + 4 * 8 * szQ + szS + szP;     // ~110 MB
    const int mode = (ws_size >= need2) ? 2 : (ws_size >= need1) ? 1 : 0;
    const int nres = (mode >= 1) ? 8 : 1;  // residency of Qt/Kt/V/ctx
    const int pres = (mode == 2) ? 8 : 1;  // residency of P

    char* ws = (char*)d_ws;
    size_t off = 0;
    auto alloc = [&](size_t bytes) {
        char* p = ws + off;
        off += (bytes + 255) & ~(size_t)255;
        return p;
    };
    __hip_bfloat16* wq_b = (__hip_bfloat16*)alloc(WB);
    __hip_bfloat16* wk_b = (__hip_bfloat16*)alloc(WB);
    __hip_bfloat16* wv_b = (__hip_bfloat16*)alloc(WB);
    __hip_bfloat16* wo_b = (__hip_bfloat16*)alloc(WB);
    __hip_bfloat16* Qt   = (__hip_bfloat16*)alloc(szQ * nres);
    __hip_bfloat16* Kt   = (__hip_bfloat16*)alloc(szQ * nres);
    __hip_bfloat16* Vb_  = (__hip_bfloat16*)alloc(szQ * nres);
    __hip_bfloat16* Ctx  = (__hip_bfloat16*)alloc(szQ * nres);
    float*          Sb   = (float*)alloc(szS);
    __hip_bfloat16* Pb_  = (__hip_bfloat16*)alloc(szP * pres);

    // weights fp32 -> bf16 (once per launch; same work every call)
    cast_f32_to_bf16<<<256, 256, 0, stream>>>(Wq, wq_b, C * C);
    cast_f32_to_bf16<<<256, 256, 0, stream>>>(Wk, wk_b, C * C);
    cast_f32_to_bf16<<<256, 256, 0, stream>>>(Wv, wv_b, C * C);
    cast_f32_to_bf16<<<256, 256, 0, stream>>>(Wo, wo_b, C * C);

    const dim3 blk(256);
    const long sIn = (long)C * N;   // fp32 input batch stride (elements)
    const long sPr = (long)N * C;   // projection batch stride (elements)

    if (mode >= 1) {
        // Batched projections over grid.z
        // Qt[n,o] = sum_c locx[c,n]*Wq[o,c] + bq[o]
        gemm_bt<1, 0, 1, 2><<<dim3(N / 128, C / 128, 8), blk, 0, stream>>>(
            locx, wq_b, Qt, bq, 1.f, N, C, C, N, C, C, sIn, 0, sPr);
        gemm_bt<1, 0, 1, 2><<<dim3(N / 128, C / 128, 8), blk, 0, stream>>>(
            glox, wk_b, Kt, bk, 1.f, N, C, C, N, C, C, sIn, 0, sPr);
        // V[o,m] = sum_c Wv[o,c]*glox[c,m] + bv[o]
        gemm_bt<0, 1, 1, 1><<<dim3(C / 128, N / 128, 8), blk, 0, stream>>>(
            wv_b, glox, Vb_, bv, 1.f, C, N, C, C, N, N, 0, sIn, sPr);
    }

    for (int b = 0; b < B; ++b) {
        const __hip_bfloat16* Qb = Qt  + (size_t)((mode >= 1) ? b : 0) * (size_t)N * C;
        const __hip_bfloat16* Kb = Kt  + (size_t)((mode >= 1) ? b : 0) * (size_t)N * C;
        const __hip_bfloat16* Vb = Vb_ + (size_t)((mode >= 1) ? b : 0) * (size_t)N * C;
        __hip_bfloat16*       Cb = Ctx + (size_t)((mode >= 1) ? b : 0) * (size_t)N * C;
        __hip_bfloat16*       Pp = Pb_ + (size_t)((mode == 2) ? b : 0) * (size_t)N * N;

        if (mode == 0) {
            gemm_bt<1, 0, 1, 2><<<dim3(N / 128, C / 128, 1), blk, 0, stream>>>(
                locx + (size_t)b * sIn, wq_b, (void*)Qb, bq, 1.f, N, C, C, N, C, C, 0, 0, 0);
            gemm_bt<1, 0, 1, 2><<<dim3(N / 128, C / 128, 1), blk, 0, stream>>>(
                glox + (size_t)b * sIn, wk_b, (void*)Kb, bk, 1.f, N, C, C, N, C, C, 0, 0, 0);
            gemm_bt<0, 1, 1, 1><<<dim3(C / 128, N / 128, 1), blk, 0, stream>>>(
                wv_b, glox + (size_t)b * sIn, (void*)Vb, bv, 1.f, C, N, C, C, N, N, 0, 0, 0);
        }

        // S[n,m] = SCALE * sum_o Qt[n,o]*Kt[m,o]   (fp32)
        gemm_bt<0, 0, 0, 0><<<dim3(N / 128, N / 128, 1), blk, 0, stream>>>(
            Qb, Kb, Sb, nullptr, ATT_SCALE, N, N, C, C, C, N, 0, 0, 0);
        // P = softmax rows, bf16
        softmax_rows<<<N, 256, 0, stream>>>(Sb, Pp);

        if (mode < 2) {
            // ctx[n,c] = sum_m P[n,m]*V[c,m]
            gemm_bt<0, 0, 1, 0><<<dim3(N / 128, C / 128, 1), blk, 0, stream>>>(
                Pp, Vb, Cb, nullptr, 1.f, N, C, N, N, N, C, 0, 0, 0);
            if (mode == 0) {
                // out[o,n] = sum_c Wo[o,c]*ctx[n,c] + bo[o]
                gemm_bt<0, 0, 0, 1><<<dim3(C / 128, N / 128, 1), blk, 0, stream>>>(
                    wo_b, Cb, out + (size_t)b * sIn, bo, 1.f, C, N, C, C, C, N, 0, 0, 0);
            }
        }
    }

    if (mode == 2) {
        gemm_bt<0, 0, 1, 0><<<dim3(N / 128, C / 128, 8), blk, 0, stream>>>(
            Pb_, Vb_, Ctx, nullptr, 1.f, N, C, N, N, N, C, (long)N * N, sPr, sPr);
    }
    if (mode >= 1) {
        gemm_bt<0, 0, 0, 1><<<dim3(C / 128, N / 128, 8), blk, 0, stream>>>(
            wo_b, Ctx, out, bo, 1.f, C, N, C, C, C, N, 0, sPr, sIn);
    }
}

// Round 2
// 489.444 us; speedup vs baseline: 1.0514x; 1.0514x over previous
//
#include <hip/hip_runtime.h>
#include <hip/hip_bf16.h>

typedef __attribute__((ext_vector_type(4))) float f32x4;
typedef __attribute__((ext_vector_type(8))) short bf16x8;
typedef __attribute__((ext_vector_type(4))) short s16x4;

#define C_DIM 512
#define N_PIX 2304
#define N_BATCH 8
#define ATT_SCALE 0.04419417382415922f

// ---------------------------------------------------------------------------
// Block-tiled bf16 MFMA GEMM:  D[i,j] = scale * sum_k A[i,k]*B[j,k] + bias
// A bf16 [I x lda] k-contiguous, B bf16 [J x ldb] k-contiguous.
// OUT_BF16: 1 -> bf16 store, 0 -> fp32 store. BIAS_MODE: 0 none, 1 per-i, 2 per-j.
// 128x128 tile, BK=64, 256 threads (4 waves), wave = 4x4 of 16x16x32 MFMAs.
// Batched via blockIdx.z with element strides sA/sB/sD.
// LS=88: row stride 44 dwords == 12 mod 32 -> 2-way bank aliasing (free, m136).
// ---------------------------------------------------------------------------
template<int OUT_BF16, int BIAS_MODE>
__global__ __launch_bounds__(256)
void gemm_bt(const __hip_bfloat16* __restrict__ A, const __hip_bfloat16* __restrict__ B,
             void* __restrict__ Dp, const float* __restrict__ bias,
             float scale, int K, int lda, int ldb, int ldd,
             long sA, long sB, long sD)
{
    constexpr int LS = 88;
    __shared__ __hip_bfloat16 As[128 * LS];
    __shared__ __hip_bfloat16 Bs[128 * LS];

    const int tid  = threadIdx.x;
    const int lane = tid & 63;
    const int wave = tid >> 6;
    const int i0 = blockIdx.x * 128;
    const int j0 = blockIdx.y * 128;
    const size_t bz = blockIdx.z;

    const __hip_bfloat16* Ab = A + bz * (size_t)sA;
    const __hip_bfloat16* Bb = B + bz * (size_t)sB;
    __hip_bfloat16* D16 = (__hip_bfloat16*)Dp + bz * (size_t)sD;
    float*          D32 = (float*)Dp          + bz * (size_t)sD;

    const int fr = lane & 15;          // fragment row (A) / col (B)
    const int fq = (lane >> 4) * 8;    // fragment k offset within 32
    const int wi = (wave >> 1) * 64;
    const int wj = (wave & 1) * 64;

    f32x4 acc[4][4];
#pragma unroll
    for (int a = 0; a < 4; ++a)
#pragma unroll
        for (int b = 0; b < 4; ++b)
            acc[a][b] = (f32x4){0.f, 0.f, 0.f, 0.f};

    for (int k0 = 0; k0 < K; k0 += 64) {
        // stage A,B tiles: 128 rows x 64 k, int4 chunks (8 bf16)
#pragma unroll
        for (int s = 0; s < 4; ++s) {
            int ch  = tid + s * 256;       // 1024 chunks
            int row = ch >> 3;
            int kc  = (ch & 7) << 3;
            *(int4*)(&As[row * LS + kc]) =
                *(const int4*)(&Ab[(size_t)(i0 + row) * lda + k0 + kc]);
            *(int4*)(&Bs[row * LS + kc]) =
                *(const int4*)(&Bb[(size_t)(j0 + row) * ldb + k0 + kc]);
        }
        __syncthreads();

#pragma unroll
        for (int kk = 0; kk < 64; kk += 32) {
            bf16x8 af[4], bfr[4];
#pragma unroll
            for (int t = 0; t < 4; ++t) {
                af[t]  = *(const bf16x8*)(&As[(wi + t * 16 + fr) * LS + kk + fq]);
                bfr[t] = *(const bf16x8*)(&Bs[(wj + t * 16 + fr) * LS + kk + fq]);
            }
#pragma unroll
            for (int a = 0; a < 4; ++a)
#pragma unroll
                for (int b = 0; b < 4; ++b)
                    acc[a][b] = __builtin_amdgcn_mfma_f32_16x16x32_bf16(
                        af[a], bfr[b], acc[a][b], 0, 0, 0);
        }
        __syncthreads();
    }

    // epilogue: D row=(lane>>4)*4+r (A index), col=lane&15 (B index)
    const int orow = (lane >> 4) * 4;
#pragma unroll
    for (int a = 0; a < 4; ++a) {
        int ib = i0 + wi + a * 16 + orow;
#pragma unroll
        for (int b = 0; b < 4; ++b) {
            int j = j0 + wj + b * 16 + fr;
            float bj = (BIAS_MODE == 2) ? bias[j] : 0.f;
#pragma unroll
            for (int r = 0; r < 4; ++r) {
                int i = ib + r;
                float v = acc[a][b][r] * scale;
                if (BIAS_MODE == 1) v += bias[i];
                if (BIAS_MODE == 2) v += bj;
                if (OUT_BF16)
                    D16[(size_t)i * ldd + j] = __float2bfloat16(v);
                else
                    D32[(size_t)i * ldd + j] = v;
            }
        }
    }
}

// ---------------------------------------------------------------------------
// Transpose + cast: X fp32 [B][C][N] -> Xt bf16 [B][N][C]. 64x64 tiles.
// Grid (N/64, C/64, B), 256 threads. LDS stride 65 -> 2-way max aliasing.
// ---------------------------------------------------------------------------
__global__ __launch_bounds__(256)
void transpose_cast(const float* __restrict__ X, __hip_bfloat16* __restrict__ Xt)
{
    __shared__ float t[64 * 65];
    const int n0 = blockIdx.x * 64;
    const int c0 = blockIdx.y * 64;
    const size_t b = blockIdx.z;
    const float* Xb = X + b * (size_t)C_DIM * N_PIX;
    const int tid = threadIdx.x;

    const int n_l = tid & 63;
    const int c_b = tid >> 6;          // 0..3
#pragma unroll
    for (int s = 0; s < 16; ++s) {
        int c_l = c_b + s * 4;
        t[c_l * 65 + n_l] = Xb[(size_t)(c0 + c_l) * N_PIX + n0 + n_l];
    }
    __syncthreads();

    const int cc = (tid & 7) * 8;
    const int nb = tid >> 3;           // 0..31
#pragma unroll
    for (int it = 0; it < 2; ++it) {
        int n2 = nb + it * 32;
        union { __hip_bfloat16 h[8]; int4 v; } u;
#pragma unroll
        for (int w = 0; w < 8; ++w)
            u.h[w] = __float2bfloat16(t[(cc + w) * 65 + n2]);
        *(int4*)(&Xt[((size_t)b * N_PIX + n0 + n2) * C_DIM + c0 + cc]) = u.v;
    }
}

// ---------------------------------------------------------------------------
// Row softmax: S fp32 [nb][N][N] -> P bf16 [nb][N][N]. One block (576 thr) per
// row, one float4 per thread. Grid (N, nb).
// ---------------------------------------------------------------------------
__global__ __launch_bounds__(576)
void softmax_rows(const float* __restrict__ S, __hip_bfloat16* __restrict__ P)
{
    const size_t roff = ((size_t)blockIdx.y * N_PIX + blockIdx.x) * N_PIX;
    const float* s = S + roff;
    __hip_bfloat16* p = P + roff;
    const int tid = threadIdx.x;

    float4 v = *(const float4*)(s + tid * 4);
    float m = fmaxf(fmaxf(v.x, v.y), fmaxf(v.z, v.w));
    __shared__ float red[9];
    for (int off = 32; off > 0; off >>= 1)
        m = fmaxf(m, __shfl_down(m, off));
    if ((tid & 63) == 0) red[tid >> 6] = m;
    __syncthreads();
    m = red[0];
#pragma unroll
    for (int w = 1; w < 9; ++w) m = fmaxf(m, red[w]);

    v.x = __expf(v.x - m); v.y = __expf(v.y - m);
    v.z = __expf(v.z - m); v.w = __expf(v.w - m);
    float sum = v.x + v.y + v.z + v.w;
    for (int off = 32; off > 0; off >>= 1)
        sum += __shfl_down(sum, off);
    __syncthreads();
    if ((tid & 63) == 0) red[tid >> 6] = sum;
    __syncthreads();
    float tot = red[0];
#pragma unroll
    for (int w = 1; w < 9; ++w) tot += red[w];
    float inv = 1.f / tot;

    union { __hip_bfloat16 h[4]; s16x4 q; } u;
    u.h[0] = __float2bfloat16(v.x * inv);
    u.h[1] = __float2bfloat16(v.y * inv);
    u.h[2] = __float2bfloat16(v.z * inv);
    u.h[3] = __float2bfloat16(v.w * inv);
    *(s16x4*)(p + tid * 4) = u.q;
}

// ---------------------------------------------------------------------------
// Cast 4 fp32 weight matrices -> contiguous bf16 buffer. Grid (C*C/1024, 4).
// ---------------------------------------------------------------------------
__global__ __launch_bounds__(256)
void cast_w4(const float* __restrict__ s0, const float* __restrict__ s1,
             const float* __restrict__ s2, const float* __restrict__ s3,
             __hip_bfloat16* __restrict__ dst)
{
    const float* srcs[4] = {s0, s1, s2, s3};
    const int w = blockIdx.y;
    const int i = (blockIdx.x * 256 + threadIdx.x) * 4;
    float4 f = *(const float4*)(srcs[w] + i);
    union { __hip_bfloat16 h[4]; s16x4 q; } t;
    t.h[0] = __float2bfloat16(f.x);
    t.h[1] = __float2bfloat16(f.y);
    t.h[2] = __float2bfloat16(f.z);
    t.h[3] = __float2bfloat16(f.w);
    *(s16x4*)(dst + (size_t)w * C_DIM * C_DIM + i) = t.q;
}

// ---------------------------------------------------------------------------
extern "C" void kernel_launch(void* const* d_in, const int* in_sizes, int n_in,
                              void* d_out, int out_size, void* d_ws, size_t ws_size,
                              hipStream_t stream)
{
    const float* locx = (const float*)d_in[0];
    const float* glox = (const float*)d_in[1];
    const float* Wq = (const float*)d_in[2];
    const float* bq = (const float*)d_in[3];
    const float* Wk = (const float*)d_in[4];
    const float* bk = (const float*)d_in[5];
    const float* Wv = (const float*)d_in[6];
    const float* bv = (const float*)d_in[7];
    const float* Wo = (const float*)d_in[8];
    const float* bo = (const float*)d_in[9];
    float* out = (float*)d_out;

    const int C = C_DIM, N = N_PIX;
    const size_t WB   = (size_t)C * C * 2;          // one bf16 weight
    const size_t szX  = (size_t)N_BATCH * N * C * 2; // batched bf16 [8,N,C]
    const size_t szS1 = (size_t)N * N * 4;           // one batch fp32 scores
    const size_t szP1 = (size_t)N * N * 2;           // one batch bf16 probs
    const size_t szP8 = szP1 * N_BATCH;

    const size_t fixed = 4 * WB + 6 * szX;           // weights + Xl,Xg,Qt,Kt,V,Ctx

    int nb = 0;            // S batches resident
    bool p8 = true;        // P fully resident?
    for (int cand : {8, 4, 2, 1})
        if (ws_size >= fixed + szP8 + (size_t)cand * szS1) { nb = cand; break; }
    if (!nb) { nb = 1; p8 = false; }

    char* ws = (char*)d_ws;
    size_t off = 0;
    auto alloc = [&](size_t bytes) {
        char* p = ws + off;
        off += (bytes + 255) & ~(size_t)255;
        return p;
    };
    __hip_bfloat16* wgt = (__hip_bfloat16*)alloc(4 * WB); // wq|wk|wv|wo contiguous
    __hip_bfloat16* Xl  = (__hip_bfloat16*)alloc(szX);
    __hip_bfloat16* Xg  = (__hip_bfloat16*)alloc(szX);
    __hip_bfloat16* Qt  = (__hip_bfloat16*)alloc(szX);
    __hip_bfloat16* Kt  = (__hip_bfloat16*)alloc(szX);
    __hip_bfloat16* Vb  = (__hip_bfloat16*)alloc(szX);
    __hip_bfloat16* Ctx = (__hip_bfloat16*)alloc(szX);
    float*          Sb  = (float*)alloc((size_t)nb * szS1);
    __hip_bfloat16* Pb  = (__hip_bfloat16*)alloc(p8 ? szP8 : szP1);

    __hip_bfloat16* wq_b = wgt;
    __hip_bfloat16* wk_b = wgt + (size_t)C * C;
    __hip_bfloat16* wv_b = wgt + 2 * (size_t)C * C;
    __hip_bfloat16* wo_b = wgt + 3 * (size_t)C * C;

    const dim3 blk(256);
    const long sPr = (long)N * C;   // [N,C] batch stride
    const long sV  = (long)C * N;   // [C,N] batch stride

    cast_w4<<<dim3(C * C / 1024, 4), blk, 0, stream>>>(Wq, Wk, Wv, Wo, wgt);
    transpose_cast<<<dim3(N / 64, C / 64, 8), blk, 0, stream>>>(locx, Xl);
    transpose_cast<<<dim3(N / 64, C / 64, 8), blk, 0, stream>>>(glox, Xg);

    // Qt[n,o] = sum_c Xl[n,c]*Wq[o,c] + bq[o]
    gemm_bt<1, 2><<<dim3(N / 128, C / 128, 8), blk, 0, stream>>>(
        Xl, wq_b, Qt, bq, 1.f, C, C, C, C, sPr, 0, sPr);
    // Kt[m,o] = sum_c Xg[m,c]*Wk[o,c] + bk[o]
    gemm_bt<1, 2><<<dim3(N / 128, C / 128, 8), blk, 0, stream>>>(
        Xg, wk_b, Kt, bk, 1.f, C, C, C, C, sPr, 0, sPr);
    // V[o,m] = sum_c Wv[o,c]*Xg[m,c] + bv[o]   (D in [C,N] layout)
    gemm_bt<1, 1><<<dim3(C / 128, N / 128, 8), blk, 0, stream>>>(
        wv_b, Xg, Vb, bv, 1.f, C, C, C, N, 0, sPr, sV);

    for (int r = 0; r < N_BATCH; r += nb) {
        // S[n,m] = SCALE * sum_o Qt[n,o]*Kt[m,o]
        gemm_bt<0, 0><<<dim3(N / 128, N / 128, nb), blk, 0, stream>>>(
            Qt + (size_t)r * sPr, Kt + (size_t)r * sPr, Sb, nullptr,
            ATT_SCALE, C, C, C, N, sPr, sPr, (long)N * N);
        __hip_bfloat16* Pr = p8 ? Pb + (size_t)r * N * N : Pb;
        softmax_rows<<<dim3(N, nb), 576, 0, stream>>>(Sb, Pr);
        if (!p8) {
            // ctx[n,c] = sum_m P[n,m]*V[c,m]   (per batch)
            gemm_bt<1, 0><<<dim3(N / 128, C / 128, 1), blk, 0, stream>>>(
                Pb, Vb + (size_t)r * sV, Ctx + (size_t)r * sPr, nullptr,
                1.f, N, N, N, C, 0, 0, 0);
        }
    }
    if (p8) {
        // ctx[n,c] = sum_m P[n,m]*V[c,m]   (batched)
        gemm_bt<1, 0><<<dim3(N / 128, C / 128, 8), blk, 0, stream>>>(
            Pb, Vb, Ctx, nullptr, 1.f, N, N, N, C, (long)N * N, sV, sPr);
    }
    // out[o,n] = sum_c Wo[o,c]*ctx[n,c] + bo[o]
    gemm_bt<0, 1><<<dim3(C / 128, N / 128, 8), blk, 0, stream>>>(
        wo_b, Ctx, out, bo, 1.f, C, C, C, N, 0, sPr, sV);
}

// Round 3
// 390.637 us; speedup vs baseline: 1.3174x; 1.2529x over previous
//
#include <hip/hip_runtime.h>
#include <hip/hip_bf16.h>

typedef __attribute__((ext_vector_type(4))) float f32x4;
typedef __attribute__((ext_vector_type(8))) short bf16x8;
typedef __attribute__((ext_vector_type(4))) short s16x4;

#define C_DIM 512
#define N_PIX 2304
#define N_BATCH 8
#define ATT_SCALE 0.04419417382415922f
#define NJB 18                      // N_PIX / 128

typedef __attribute__((address_space(3))) unsigned int lds_u32;
typedef const __attribute__((address_space(1))) unsigned int glob_u32;

__device__ __forceinline__ void gl2lds16(const __hip_bfloat16* g, __hip_bfloat16* l)
{
    // async 16B-per-lane global->LDS; LDS dest = wave-uniform base + lane*16 (m104)
    __builtin_amdgcn_global_load_lds((glob_u32*)g, (lds_u32*)l, 16, 0, 0);
}

// ---------------------------------------------------------------------------
// m97-style bf16 MFMA GEMM: D[i,j] = scale * sum_k A[i,k]*B[j,k] (+bias)
// A [I x lda] k-contig, B [J x ldb] k-contig, 128x128 tile, BK=64, 4 waves.
// Staging via global_load_lds w/ XOR swizzle: LDS slot (row, chunk cc) holds
// global chunk cc^(row&7); ds_read applies same XOR -> 2-way max bank alias.
// EPI: 0 plain; 1 = store exp(v) bf16 + write per-jblock rowsum partials to
//      rsum[(jb*8+bz)*N + i]; 2 = multiply by rinv[bz*N + i] (PV normalize).
// ---------------------------------------------------------------------------
template<int OUT_BF16, int BIAS_MODE, int EPI>
__global__ __launch_bounds__(256)
void gemm_bt(const __hip_bfloat16* __restrict__ A, const __hip_bfloat16* __restrict__ B,
             void* __restrict__ Dp, const float* __restrict__ bias,
             float* __restrict__ rsum,
             float scale, int K, int lda, int ldb, int ldd,
             long sA, long sB, long sD)
{
    __shared__ __hip_bfloat16 As[128 * 64];
    __shared__ __hip_bfloat16 Bs[128 * 64];

    const int tid  = threadIdx.x;
    const int lane = tid & 63;
    const int wave = tid >> 6;
    const int i0 = blockIdx.x * 128;
    const int j0 = blockIdx.y * 128;
    const size_t bz = blockIdx.z;

    const __hip_bfloat16* Ab = A + bz * (size_t)sA;
    const __hip_bfloat16* Bb = B + bz * (size_t)sB;
    __hip_bfloat16* D16 = (__hip_bfloat16*)Dp + bz * (size_t)sD;
    float*          D32 = (float*)Dp          + bz * (size_t)sD;

    // staging addresses: wave w covers rows [w*32, w*32+32), 4 instrs of 8 rows
    const int lrow = lane >> 3;                 // 0..7 within 8-row group
    const int lcs  = (lane & 7) ^ lrow;         // swizzled source chunk
    const __hip_bfloat16* ga = Ab + (size_t)(i0 + wave * 32 + lrow) * lda + lcs * 8;
    const __hip_bfloat16* gb = Bb + (size_t)(j0 + wave * 32 + lrow) * ldb + lcs * 8;
    __hip_bfloat16* la = As + wave * 32 * 64;
    __hip_bfloat16* lb = Bs + wave * 32 * 64;

    const int fr = lane & 15;
    const int fq = lane >> 4;                   // 0..3
    const int sw = fr & 7;                      // read-side swizzle key
    const int wi = (wave >> 1) * 64;
    const int wj = (wave & 1) * 64;

    f32x4 acc[4][4];
#pragma unroll
    for (int a = 0; a < 4; ++a)
#pragma unroll
        for (int b = 0; b < 4; ++b)
            acc[a][b] = (f32x4){0.f, 0.f, 0.f, 0.f};

    for (int k0 = 0; k0 < K; k0 += 64) {
#pragma unroll
        for (int s = 0; s < 4; ++s) {
            gl2lds16(ga + (size_t)s * 8 * lda + k0, la + s * 8 * 64);
            gl2lds16(gb + (size_t)s * 8 * ldb + k0, lb + s * 8 * 64);
        }
        __syncthreads();

#pragma unroll
        for (int kk = 0; kk < 2; ++kk) {
            bf16x8 af[4], bfr[4];
            const int ca = ((kk * 4 + fq) ^ sw) << 3;
#pragma unroll
            for (int t = 0; t < 4; ++t) {
                af[t]  = *(const bf16x8*)(&As[(wi + t * 16 + fr) * 64 + ca]);
                bfr[t] = *(const bf16x8*)(&Bs[(wj + t * 16 + fr) * 64 + ca]);
            }
#pragma unroll
            for (int a = 0; a < 4; ++a)
#pragma unroll
                for (int b = 0; b < 4; ++b)
                    acc[a][b] = __builtin_amdgcn_mfma_f32_16x16x32_bf16(
                        af[a], bfr[b], acc[a][b], 0, 0, 0);
        }
        __syncthreads();
    }

    // epilogue: C/D map: row = (lane>>4)*4 + r, col = lane&15 per 16x16 tile
    const int orow = fq * 4;

    float inv[4][4];
    if (EPI == 2) {
        const float* ri = rsum + bz * N_PIX;
#pragma unroll
        for (int a = 0; a < 4; ++a)
#pragma unroll
            for (int r = 0; r < 4; ++r)
                inv[a][r] = ri[i0 + wi + a * 16 + orow + r];
    }

    float rpart[4][4];
    if (EPI == 1) {
#pragma unroll
        for (int a = 0; a < 4; ++a)
#pragma unroll
            for (int r = 0; r < 4; ++r)
                rpart[a][r] = 0.f;
    }

#pragma unroll
    for (int a = 0; a < 4; ++a) {
        int ib = i0 + wi + a * 16 + orow;
#pragma unroll
        for (int b = 0; b < 4; ++b) {
            int j = j0 + wj + b * 16 + fr;
            float bj = (BIAS_MODE == 2) ? bias[j] : 0.f;
#pragma unroll
            for (int r = 0; r < 4; ++r) {
                int i = ib + r;
                float v = acc[a][b][r] * scale;
                if (BIAS_MODE == 1) v += bias[i];
                if (BIAS_MODE == 2) v += bj;
                if (EPI == 1) { v = __expf(v); rpart[a][r] += v; }
                if (EPI == 2) v *= inv[a][r];
                if (OUT_BF16)
                    D16[(size_t)i * ldd + j] = __float2bfloat16(v);
                else
                    D32[(size_t)i * ldd + j] = v;
            }
        }
    }

    if (EPI == 1) {
        // reduce rpart across the 16 fr-lanes (bits 0..3 of lane)
#pragma unroll
        for (int m = 1; m < 16; m <<= 1)
#pragma unroll
            for (int a = 0; a < 4; ++a)
#pragma unroll
                for (int r = 0; r < 4; ++r)
                    rpart[a][r] += __shfl_xor(rpart[a][r], m);
        float* rsl = (float*)As;   // reuse LDS (all ds_reads drained at last barrier)
        if (fr == 0) {
#pragma unroll
            for (int a = 0; a < 4; ++a)
#pragma unroll
                for (int r = 0; r < 4; ++r)
                    rsl[wave * 64 + a * 16 + orow + r] = rpart[a][r];
        }
        __syncthreads();
        if (tid < 128) {
            int half = tid >> 6, rr = tid & 63;
            float s = rsl[(half * 2) * 64 + rr] + rsl[(half * 2 + 1) * 64 + rr];
            rsum[((size_t)blockIdx.y * N_BATCH + bz) * N_PIX + i0 + tid] = s;
        }
    }
}

// ---------------------------------------------------------------------------
// rinv[idx] = 1 / sum_jb rp[jb*8*N + idx], idx over nb*N (batch-major, stride N)
// ---------------------------------------------------------------------------
__global__ __launch_bounds__(256)
void reduce_rinv(const float* __restrict__ rp, float* __restrict__ rinv)
{
    int idx = blockIdx.x * 256 + threadIdx.x;
    float s = 0.f;
#pragma unroll
    for (int jb = 0; jb < NJB; ++jb)
        s += rp[(size_t)jb * N_BATCH * N_PIX + idx];
    rinv[idx] = 1.f / s;
}

// ---------------------------------------------------------------------------
// Transpose + cast: X fp32 [B][C][N] -> Xt bf16 [B][N][C]. 64x64 tiles.
// ---------------------------------------------------------------------------
__global__ __launch_bounds__(256)
void transpose_cast(const float* __restrict__ X, __hip_bfloat16* __restrict__ Xt)
{
    __shared__ float t[64 * 65];
    const int n0 = blockIdx.x * 64;
    const int c0 = blockIdx.y * 64;
    const size_t b = blockIdx.z;
    const float* Xb = X + b * (size_t)C_DIM * N_PIX;
    const int tid = threadIdx.x;

    const int n_l = tid & 63;
    const int c_b = tid >> 6;
#pragma unroll
    for (int s = 0; s < 16; ++s) {
        int c_l = c_b + s * 4;
        t[c_l * 65 + n_l] = Xb[(size_t)(c0 + c_l) * N_PIX + n0 + n_l];
    }
    __syncthreads();

    const int cc = (tid & 7) * 8;
    const int nb = tid >> 3;
#pragma unroll
    for (int it = 0; it < 2; ++it) {
        int n2 = nb + it * 32;
        union { __hip_bfloat16 h[8]; int4 v; } u;
#pragma unroll
        for (int w = 0; w < 8; ++w)
            u.h[w] = __float2bfloat16(t[(cc + w) * 65 + n2]);
        *(int4*)(&Xt[((size_t)b * N_PIX + n0 + n2) * C_DIM + c0 + cc]) = u.v;
    }
}

// ---------------------------------------------------------------------------
__global__ __launch_bounds__(256)
void cast_w4(const float* __restrict__ s0, const float* __restrict__ s1,
             const float* __restrict__ s2, const float* __restrict__ s3,
             __hip_bfloat16* __restrict__ dst)
{
    const float* srcs[4] = {s0, s1, s2, s3};
    const int w = blockIdx.y;
    const int i = (blockIdx.x * 256 + threadIdx.x) * 4;
    float4 f = *(const float4*)(srcs[w] + i);
    union { __hip_bfloat16 h[4]; s16x4 q; } t;
    t.h[0] = __float2bfloat16(f.x);
    t.h[1] = __float2bfloat16(f.y);
    t.h[2] = __float2bfloat16(f.z);
    t.h[3] = __float2bfloat16(f.w);
    *(s16x4*)(dst + (size_t)w * C_DIM * C_DIM + i) = t.q;
}

// ---------------------------------------------------------------------------
extern "C" void kernel_launch(void* const* d_in, const int* in_sizes, int n_in,
                              void* d_out, int out_size, void* d_ws, size_t ws_size,
                              hipStream_t stream)
{
    const float* locx = (const float*)d_in[0];
    const float* glox = (const float*)d_in[1];
    const float* Wq = (const float*)d_in[2];
    const float* bq = (const float*)d_in[3];
    const float* Wk = (const float*)d_in[4];
    const float* bk = (const float*)d_in[5];
    const float* Wv = (const float*)d_in[6];
    const float* bv = (const float*)d_in[7];
    const float* Wo = (const float*)d_in[8];
    const float* bo = (const float*)d_in[9];
    float* out = (float*)d_out;

    const int C = C_DIM, N = N_PIX;
    const size_t WB   = (size_t)C * C * 2;
    const size_t szX  = (size_t)N_BATCH * N * C * 2;   // 18.87 MB
    const size_t szP1 = (size_t)N * N * 2;             // 10.6 MB / batch
    const size_t szRP = (size_t)NJB * N_BATCH * N * 4; // rowsum partials
    const size_t szRI = (size_t)N_BATCH * N * 4;

    const size_t fixed = 4 * WB + 6 * szX + szRP + szRI;
    int nb = 1;
    for (int cand : {8, 4, 2, 1})
        if (ws_size >= fixed + (size_t)cand * szP1 + 8 * 256) { nb = cand; break; }

    char* ws = (char*)d_ws;
    size_t off = 0;
    auto alloc = [&](size_t bytes) {
        char* p = ws + off;
        off += (bytes + 255) & ~(size_t)255;
        return p;
    };
    __hip_bfloat16* wgt = (__hip_bfloat16*)alloc(4 * WB);
    __hip_bfloat16* Xl  = (__hip_bfloat16*)alloc(szX);
    __hip_bfloat16* Xg  = (__hip_bfloat16*)alloc(szX);
    __hip_bfloat16* Qt  = (__hip_bfloat16*)alloc(szX);
    __hip_bfloat16* Kt  = (__hip_bfloat16*)alloc(szX);
    __hip_bfloat16* Vb  = (__hip_bfloat16*)alloc(szX);
    __hip_bfloat16* Ctx = (__hip_bfloat16*)alloc(szX);
    float*          rp   = (float*)alloc(szRP);
    float*          rinv = (float*)alloc(szRI);
    __hip_bfloat16* Pu  = (__hip_bfloat16*)alloc((size_t)nb * szP1);

    __hip_bfloat16* wq_b = wgt;
    __hip_bfloat16* wk_b = wgt + (size_t)C * C;
    __hip_bfloat16* wv_b = wgt + 2 * (size_t)C * C;
    __hip_bfloat16* wo_b = wgt + 3 * (size_t)C * C;

    const dim3 blk(256);
    const long sPr = (long)N * C;   // [N,C] batch stride
    const long sV  = (long)C * N;   // [C,N] batch stride

    cast_w4<<<dim3(C * C / 1024, 4), blk, 0, stream>>>(Wq, Wk, Wv, Wo, wgt);
    transpose_cast<<<dim3(N / 64, C / 64, 8), blk, 0, stream>>>(locx, Xl);
    transpose_cast<<<dim3(N / 64, C / 64, 8), blk, 0, stream>>>(glox, Xg);

    // Qt[n,o] = sum_c Xl[n,c]*Wq[o,c] + bq[o]
    gemm_bt<1, 2, 0><<<dim3(N / 128, C / 128, 8), blk, 0, stream>>>(
        Xl, wq_b, Qt, bq, nullptr, 1.f, C, C, C, C, sPr, 0, sPr);
    // Kt[m,o] = sum_c Xg[m,c]*Wk[o,c] + bk[o]
    gemm_bt<1, 2, 0><<<dim3(N / 128, C / 128, 8), blk, 0, stream>>>(
        Xg, wk_b, Kt, bk, nullptr, 1.f, C, C, C, C, sPr, 0, sPr);
    // V[o,m] = sum_c Wv[o,c]*Xg[m,c] + bv[o]   (layout [C,N])
    gemm_bt<1, 1, 0><<<dim3(C / 128, N / 128, 8), blk, 0, stream>>>(
        wv_b, Xg, Vb, bv, nullptr, 1.f, C, C, C, N, 0, sPr, sV);

    for (int r = 0; r < N_BATCH; r += nb) {
        // Pu[n,m] = exp(SCALE * sum_o Qt[n,o]*Kt[m,o]); rowsum partials -> rp
        gemm_bt<1, 0, 1><<<dim3(N / 128, N / 128, nb), blk, 0, stream>>>(
            Qt + (size_t)r * sPr, Kt + (size_t)r * sPr, Pu, nullptr,
            rp + (size_t)r * N, ATT_SCALE, C, C, C, N, sPr, sPr, (long)N * N);
        // rinv = 1 / rowsum
        reduce_rinv<<<dim3(nb * N / 256), blk, 0, stream>>>(
            rp + (size_t)r * N, rinv + (size_t)r * N);
        // ctx[n,c] = (sum_m Pu[n,m]*V[c,m]) * rinv[n]
        gemm_bt<1, 0, 2><<<dim3(N / 128, C / 128, nb), blk, 0, stream>>>(
            Pu, Vb + (size_t)r * sV, Ctx + (size_t)r * sPr, nullptr,
            rinv + (size_t)r * N, 1.f, N, N, N, C, (long)N * N, sV, sPr);
    }

    // out[o,n] = sum_c Wo[o,c]*ctx[n,c] + bo[o]   (fp32, layout [C,N])
    gemm_bt<0, 1, 0><<<dim3(C / 128, N / 128, 8), blk, 0, stream>>>(
        wo_b, Ctx, out, bo, nullptr, 1.f, C, C, C, N, 0, sPr, sV);
}

// Round 4
// 368.222 us; speedup vs baseline: 1.3976x; 1.0609x over previous
//
#include <hip/hip_runtime.h>
#include <hip/hip_bf16.h>

typedef __attribute__((ext_vector_type(4))) float f32x4;
typedef __attribute__((ext_vector_type(8))) short bf16x8;
typedef __attribute__((ext_vector_type(4))) short s16x4;

#define C_DIM 512
#define N_PIX 2304
#define N_BATCH 8
#define ATT_SCALE 0.04419417382415922f
#define NJB 18                      // N_PIX / 128

typedef __attribute__((address_space(3))) unsigned int lds_u32;
typedef const __attribute__((address_space(1))) unsigned int glob_u32;

__device__ __forceinline__ void gl2lds16(const __hip_bfloat16* g, __hip_bfloat16* l)
{
    __builtin_amdgcn_global_load_lds((glob_u32*)g, (lds_u32*)l, 16, 0, 0);
}

// ---------------------------------------------------------------------------
// m97-style bf16 MFMA GEMM: D[i,j] = scale * sum_k A[i,k]*B[j,k] (+bias)
// 128x128 tile, BK=64, 4 waves, global_load_lds staging w/ XOR swizzle.
// 1-D grid, XCD-aware decode:  s = lin % NS (batch/slot -> XCD = lin%8),
//   t = lin / NS, j-tile = t % NJ (fast: shares A-tile), i-tile = t / NJ.
// MERGE2: NS=16, slot s>>3 selects (A1,B1,bias1,D1) -> fused Q+K projection.
// EPI: 0 plain; 1 = store exp(v) + rowsum partials rsum[(j*8+bz)*N + i];
//      2 = multiply by rinv[bz*N + i]  (PV normalization).
// ---------------------------------------------------------------------------
template<int OUT_BF16, int BIAS_MODE, int EPI, int MERGE2, int NJ, int NS>
__global__ __launch_bounds__(256)
void gemm_bt(const __hip_bfloat16* __restrict__ A0, const __hip_bfloat16* __restrict__ B0,
             void* __restrict__ D0, const float* __restrict__ bias0,
             float* __restrict__ rsum,
             const __hip_bfloat16* __restrict__ A1, const __hip_bfloat16* __restrict__ B1,
             void* __restrict__ D1, const float* __restrict__ bias1,
             float scale, int K, int lda, int ldb, int ldd,
             long sA, long sB, long sD)
{
    __shared__ __hip_bfloat16 As[128 * 64];
    __shared__ __hip_bfloat16 Bs[128 * 64];

    const int lin = blockIdx.x;
    const int s   = lin % NS;
    const int t   = lin / NS;
    const int bz  = MERGE2 ? (s & 7) : s;
    const int jb  = t % NJ;
    const int j0  = jb * 128;
    const int i0  = (t / NJ) * 128;

    const __hip_bfloat16* A = A0;
    const __hip_bfloat16* B = B0;
    void* Dp = (void*)D0;
    const float* bias = bias0;
    if (MERGE2 && (s >> 3)) { A = A1; B = B1; Dp = D1; bias = bias1; }

    const int tid  = threadIdx.x;
    const int lane = tid & 63;
    const int wave = tid >> 6;

    const __hip_bfloat16* Ab = A + (size_t)bz * (size_t)sA;
    const __hip_bfloat16* Bb = B + (size_t)bz * (size_t)sB;
    __hip_bfloat16* D16 = (__hip_bfloat16*)Dp + (size_t)bz * (size_t)sD;
    float*          D32 = (float*)Dp          + (size_t)bz * (size_t)sD;

    // staging: wave w covers rows [w*32, w*32+32), 4 instrs of 8 rows each
    const int lrow = lane >> 3;
    const int lcs  = (lane & 7) ^ lrow;         // XOR-swizzled source chunk
    const __hip_bfloat16* ga = Ab + (size_t)(i0 + wave * 32 + lrow) * lda + lcs * 8;
    const __hip_bfloat16* gb = Bb + (size_t)(j0 + wave * 32 + lrow) * ldb + lcs * 8;
    __hip_bfloat16* la = As + wave * 32 * 64;
    __hip_bfloat16* lb = Bs + wave * 32 * 64;

    const int fr = lane & 15;
    const int fq = lane >> 4;                   // 0..3
    const int sw = fr & 7;
    const int wi = (wave >> 1) * 64;
    const int wj = (wave & 1) * 64;

    f32x4 acc[4][4];
#pragma unroll
    for (int a = 0; a < 4; ++a)
#pragma unroll
        for (int b = 0; b < 4; ++b)
            acc[a][b] = (f32x4){0.f, 0.f, 0.f, 0.f};

    for (int k0 = 0; k0 < K; k0 += 64) {
#pragma unroll
        for (int ss = 0; ss < 4; ++ss) {
            gl2lds16(ga + (size_t)ss * 8 * lda + k0, la + ss * 8 * 64);
            gl2lds16(gb + (size_t)ss * 8 * ldb + k0, lb + ss * 8 * 64);
        }
        __syncthreads();

#pragma unroll
        for (int kk = 0; kk < 2; ++kk) {
            bf16x8 af[4], bfr[4];
            const int ca = ((kk * 4 + fq) ^ sw) << 3;
#pragma unroll
            for (int tt = 0; tt < 4; ++tt) {
                af[tt]  = *(const bf16x8*)(&As[(wi + tt * 16 + fr) * 64 + ca]);
                bfr[tt] = *(const bf16x8*)(&Bs[(wj + tt * 16 + fr) * 64 + ca]);
            }
#pragma unroll
            for (int a = 0; a < 4; ++a)
#pragma unroll
                for (int b = 0; b < 4; ++b)
                    acc[a][b] = __builtin_amdgcn_mfma_f32_16x16x32_bf16(
                        af[a], bfr[b], acc[a][b], 0, 0, 0);
        }
        __syncthreads();
    }

    // epilogue: C/D map row = fq*4 + r, col = fr per 16x16 tile
    const int orow = fq * 4;

    float inv[4][4];
    if (EPI == 2) {
        const float* ri = rsum + (size_t)bz * N_PIX;
#pragma unroll
        for (int a = 0; a < 4; ++a)
#pragma unroll
            for (int r = 0; r < 4; ++r)
                inv[a][r] = ri[i0 + wi + a * 16 + orow + r];
    }

    float rpart[4][4];
    if (EPI == 1) {
#pragma unroll
        for (int a = 0; a < 4; ++a)
#pragma unroll
            for (int r = 0; r < 4; ++r)
                rpart[a][r] = 0.f;
    }

#pragma unroll
    for (int a = 0; a < 4; ++a) {
        int ib = i0 + wi + a * 16 + orow;
#pragma unroll
        for (int b = 0; b < 4; ++b) {
            int j = j0 + wj + b * 16 + fr;
            float bj = (BIAS_MODE == 2) ? bias[j] : 0.f;
#pragma unroll
            for (int r = 0; r < 4; ++r) {
                int i = ib + r;
                float v = acc[a][b][r] * scale;
                if (BIAS_MODE == 1) v += bias[i];
                if (BIAS_MODE == 2) v += bj;
                if (EPI == 1) { v = __expf(v); rpart[a][r] += v; }
                if (EPI == 2) v *= inv[a][r];
                if (OUT_BF16)
                    D16[(size_t)i * ldd + j] = __float2bfloat16(v);
                else
                    D32[(size_t)i * ldd + j] = v;
            }
        }
    }

    if (EPI == 1) {
#pragma unroll
        for (int m = 1; m < 16; m <<= 1)
#pragma unroll
            for (int a = 0; a < 4; ++a)
#pragma unroll
                for (int r = 0; r < 4; ++r)
                    rpart[a][r] += __shfl_xor(rpart[a][r], m);
        float* rsl = (float*)As;
        if (fr == 0) {
#pragma unroll
            for (int a = 0; a < 4; ++a)
#pragma unroll
                for (int r = 0; r < 4; ++r)
                    rsl[wave * 64 + a * 16 + orow + r] = rpart[a][r];
        }
        __syncthreads();
        if (tid < 128) {
            int half = tid >> 6, rr = tid & 63;
            float sm = rsl[(half * 2) * 64 + rr] + rsl[(half * 2 + 1) * 64 + rr];
            rsum[((size_t)jb * N_BATCH + bz) * N_PIX + i0 + tid] = sm;
        }
    }
}

// ---------------------------------------------------------------------------
__global__ __launch_bounds__(256)
void reduce_rinv(const float* __restrict__ rp, float* __restrict__ rinv)
{
    int idx = blockIdx.x * 256 + threadIdx.x;
    float s = 0.f;
#pragma unroll
    for (int jb = 0; jb < NJB; ++jb)
        s += rp[(size_t)jb * N_BATCH * N_PIX + idx];
    rinv[idx] = 1.f / s;
}

// ---------------------------------------------------------------------------
__global__ __launch_bounds__(256)
void transpose_cast(const float* __restrict__ X, __hip_bfloat16* __restrict__ Xt)
{
    __shared__ float t[64 * 65];
    const int n0 = blockIdx.x * 64;
    const int c0 = blockIdx.y * 64;
    const size_t b = blockIdx.z;
    const float* Xb = X + b * (size_t)C_DIM * N_PIX;
    const int tid = threadIdx.x;

    const int n_l = tid & 63;
    const int c_b = tid >> 6;
#pragma unroll
    for (int s = 0; s < 16; ++s) {
        int c_l = c_b + s * 4;
        t[c_l * 65 + n_l] = Xb[(size_t)(c0 + c_l) * N_PIX + n0 + n_l];
    }
    __syncthreads();

    const int cc = (tid & 7) * 8;
    const int nb = tid >> 3;
#pragma unroll
    for (int it = 0; it < 2; ++it) {
        int n2 = nb + it * 32;
        union { __hip_bfloat16 h[8]; int4 v; } u;
#pragma unroll
        for (int w = 0; w < 8; ++w)
            u.h[w] = __float2bfloat16(t[(cc + w) * 65 + n2]);
        *(int4*)(&Xt[((size_t)b * N_PIX + n0 + n2) * C_DIM + c0 + cc]) = u.v;
    }
}

// ---------------------------------------------------------------------------
__global__ __launch_bounds__(256)
void cast_w4(const float* __restrict__ s0, const float* __restrict__ s1,
             const float* __restrict__ s2, const float* __restrict__ s3,
             __hip_bfloat16* __restrict__ dst)
{
    const float* srcs[4] = {s0, s1, s2, s3};
    const int w = blockIdx.y;
    const int i = (blockIdx.x * 256 + threadIdx.x) * 4;
    float4 f = *(const float4*)(srcs[w] + i);
    union { __hip_bfloat16 h[4]; s16x4 q; } t;
    t.h[0] = __float2bfloat16(f.x);
    t.h[1] = __float2bfloat16(f.y);
    t.h[2] = __float2bfloat16(f.z);
    t.h[3] = __float2bfloat16(f.w);
    *(s16x4*)(dst + (size_t)w * C_DIM * C_DIM + i) = t.q;
}

// ---------------------------------------------------------------------------
extern "C" void kernel_launch(void* const* d_in, const int* in_sizes, int n_in,
                              void* d_out, int out_size, void* d_ws, size_t ws_size,
                              hipStream_t stream)
{
    const float* locx = (const float*)d_in[0];
    const float* glox = (const float*)d_in[1];
    const float* Wq = (const float*)d_in[2];
    const float* bq = (const float*)d_in[3];
    const float* Wk = (const float*)d_in[4];
    const float* bk = (const float*)d_in[5];
    const float* Wv = (const float*)d_in[6];
    const float* bv = (const float*)d_in[7];
    const float* Wo = (const float*)d_in[8];
    const float* bo = (const float*)d_in[9];
    float* out = (float*)d_out;

    const int C = C_DIM, N = N_PIX;
    const size_t WB   = (size_t)C * C * 2;
    const size_t szX  = (size_t)N_BATCH * N * C * 2;
    const size_t szP1 = (size_t)N * N * 2;
    const size_t szRP = (size_t)NJB * N_BATCH * N * 4;
    const size_t szRI = (size_t)N_BATCH * N * 4;

    const size_t fixed = 4 * WB + 6 * szX + szRP + szRI;
    bool full = (ws_size >= fixed + 8 * szP1 + 8 * 256);

    char* ws = (char*)d_ws;
    size_t off = 0;
    auto alloc = [&](size_t bytes) {
        char* p = ws + off;
        off += (bytes + 255) & ~(size_t)255;
        return p;
    };
    __hip_bfloat16* wgt = (__hip_bfloat16*)alloc(4 * WB);
    __hip_bfloat16* Xl  = (__hip_bfloat16*)alloc(szX);
    __hip_bfloat16* Xg  = (__hip_bfloat16*)alloc(szX);
    __hip_bfloat16* Qt  = (__hip_bfloat16*)alloc(szX);
    __hip_bfloat16* Kt  = (__hip_bfloat16*)alloc(szX);
    __hip_bfloat16* Vb  = (__hip_bfloat16*)alloc(szX);
    __hip_bfloat16* Ctx = (__hip_bfloat16*)alloc(szX);
    float*          rp   = (float*)alloc(szRP);
    float*          rinv = (float*)alloc(szRI);
    __hip_bfloat16* Pu  = (__hip_bfloat16*)alloc(full ? 8 * szP1 : szP1);

    __hip_bfloat16* wq_b = wgt;
    __hip_bfloat16* wk_b = wgt + (size_t)C * C;
    __hip_bfloat16* wv_b = wgt + 2 * (size_t)C * C;
    __hip_bfloat16* wo_b = wgt + 3 * (size_t)C * C;

    const dim3 blk(256);
    const long sPr = (long)N * C;   // [N,C] batch stride
    const long sV  = (long)C * N;   // [C,N] batch stride

    cast_w4<<<dim3(C * C / 1024, 4), blk, 0, stream>>>(Wq, Wk, Wv, Wo, wgt);
    transpose_cast<<<dim3(N / 64, C / 64, 8), blk, 0, stream>>>(locx, Xl);
    transpose_cast<<<dim3(N / 64, C / 64, 8), blk, 0, stream>>>(glox, Xg);

    // merged Q+K projection: slot<8 -> Q (Xl,wq,bq->Qt), slot>=8 -> K
    gemm_bt<1, 2, 0, 1, 4, 16><<<dim3(18 * 4 * 16), blk, 0, stream>>>(
        Xl, wq_b, Qt, bq, nullptr, Xg, wk_b, Kt, bk,
        1.f, C, C, C, C, sPr, 0, sPr);
    // V[o,m] = sum_c Wv[o,c]*Xg[m,c] + bv[o]   (layout [C,N])
    gemm_bt<1, 1, 0, 0, 18, 8><<<dim3(4 * 18 * 8), blk, 0, stream>>>(
        wv_b, Xg, Vb, bv, nullptr, nullptr, nullptr, nullptr, nullptr,
        1.f, C, C, C, N, 0, sPr, sV);

    if (full) {
        // Pu = exp(SCALE * Qt Kt^T), rowsum partials -> rp
        gemm_bt<1, 0, 1, 0, 18, 8><<<dim3(18 * 18 * 8), blk, 0, stream>>>(
            Qt, Kt, Pu, nullptr, rp, nullptr, nullptr, nullptr, nullptr,
            ATT_SCALE, C, C, C, N, sPr, sPr, (long)N * N);
        reduce_rinv<<<dim3(8 * N / 256), blk, 0, stream>>>(rp, rinv);
        // ctx = (Pu V^T) * rinv
        gemm_bt<1, 0, 2, 0, 4, 8><<<dim3(18 * 4 * 8), blk, 0, stream>>>(
            Pu, Vb, Ctx, nullptr, rinv, nullptr, nullptr, nullptr, nullptr,
            1.f, N, N, N, C, (long)N * N, sV, sPr);
    } else {
        for (int r = 0; r < N_BATCH; ++r) {
            gemm_bt<1, 0, 1, 0, 18, 1><<<dim3(18 * 18), blk, 0, stream>>>(
                Qt + (size_t)r * sPr, Kt + (size_t)r * sPr, Pu, nullptr,
                rp + (size_t)r * N, nullptr, nullptr, nullptr, nullptr,
                ATT_SCALE, C, C, C, N, 0, 0, 0);
            reduce_rinv<<<dim3(N / 256), blk, 0, stream>>>(
                rp + (size_t)r * N, rinv + (size_t)r * N);
            gemm_bt<1, 0, 2, 0, 4, 1><<<dim3(18 * 4), blk, 0, stream>>>(
                Pu, Vb + (size_t)r * sV, Ctx + (size_t)r * sPr, nullptr,
                rinv + (size_t)r * N, nullptr, nullptr, nullptr, nullptr,
                1.f, N, N, N, C, 0, 0, 0);
        }
    }

    // out[o,n] = sum_c Wo[o,c]*ctx[n,c] + bo[o]   (fp32)
    gemm_bt<0, 1, 0, 0, 18, 8><<<dim3(4 * 18 * 8), blk, 0, stream>>>(
        wo_b, Ctx, out, bo, nullptr, nullptr, nullptr, nullptr, nullptr,
        1.f, C, C, C, N, 0, sPr, (long)C * N);
}

// Round 5
// 339.833 us; speedup vs baseline: 1.5143x; 1.0835x over previous
//
#include <hip/hip_runtime.h>
#include <hip/hip_bf16.h>

typedef __attribute__((ext_vector_type(4))) float f32x4;
typedef __attribute__((ext_vector_type(8))) short bf16x8;
typedef __attribute__((ext_vector_type(4))) short s16x4;

#define C_DIM 512
#define N_PIX 2304
#define N_BATCH 8
#define ATT_SCALE 0.04419417382415922f
#define NJB 18                      // N_PIX / 128

typedef __attribute__((address_space(3))) unsigned int lds_u32;
typedef const __attribute__((address_space(1))) unsigned int glob_u32;

__device__ __forceinline__ void gl2lds16(const __hip_bfloat16* g, __hip_bfloat16* l)
{
    __builtin_amdgcn_global_load_lds((glob_u32*)g, (lds_u32*)l, 16, 0, 0);
}

// ---------------------------------------------------------------------------
// m97-style bf16 MFMA GEMM: D[i,j] = scale * sum_k A[i,k]*B[j,k] (+bias)
// 128x128 tile, BK=64, 4 waves, global_load_lds staging w/ XOR swizzle.
// 1-D grid: s = lin % NS (batch -> XCD = lin%8), t = lin / NS;
//   IFAST=0: jb = t % NJ (fast, shares A-tile), ib = t / NJ
//   IFAST=1: ib = t % NI (fast, shares B-tile), jb = t / NI
// EPI: 0 plain; 1 = store exp(v) + rowsum partials rsum[(jb*8+bz)*N + i];
//      3 = v = v*rinv[bz*N + j] + bias_i  (PV epilogue, fp32 out)
// ---------------------------------------------------------------------------
template<int OUT_BF16, int BIAS_MODE, int EPI, int NJ, int NS, int IFAST, int NI>
__global__ __launch_bounds__(256)
void gemm_bt(const __hip_bfloat16* __restrict__ A, const __hip_bfloat16* __restrict__ B,
             void* __restrict__ Dp, const float* __restrict__ bias,
             float* __restrict__ rsum,
             float scale, int K, int lda, int ldb, int ldd,
             long sA, long sB, long sD)
{
    __shared__ __hip_bfloat16 As[128 * 64];
    __shared__ __hip_bfloat16 Bs[128 * 64];

    const int lin = blockIdx.x;
    const int s   = lin % NS;
    const int t   = lin / NS;
    const int bz  = s;
    int ib, jb;
    if (IFAST) { ib = t % NI; jb = t / NI; }
    else       { jb = t % NJ; ib = t / NJ; }
    const int i0 = ib * 128;
    const int j0 = jb * 128;

    const int tid  = threadIdx.x;
    const int lane = tid & 63;
    const int wave = tid >> 6;

    const __hip_bfloat16* Ab = A + (size_t)bz * (size_t)sA;
    const __hip_bfloat16* Bb = B + (size_t)bz * (size_t)sB;
    __hip_bfloat16* D16 = (__hip_bfloat16*)Dp + (size_t)bz * (size_t)sD;
    float*          D32 = (float*)Dp          + (size_t)bz * (size_t)sD;

    const int lrow = lane >> 3;
    const int lcs  = (lane & 7) ^ lrow;         // XOR-swizzled source chunk
    const __hip_bfloat16* ga = Ab + (size_t)(i0 + wave * 32 + lrow) * lda + lcs * 8;
    const __hip_bfloat16* gb = Bb + (size_t)(j0 + wave * 32 + lrow) * ldb + lcs * 8;
    __hip_bfloat16* la = As + wave * 32 * 64;
    __hip_bfloat16* lb = Bs + wave * 32 * 64;

    const int fr = lane & 15;
    const int fq = lane >> 4;
    const int sw = fr & 7;
    const int wi = (wave >> 1) * 64;
    const int wj = (wave & 1) * 64;

    f32x4 acc[4][4];
#pragma unroll
    for (int a = 0; a < 4; ++a)
#pragma unroll
        for (int b = 0; b < 4; ++b)
            acc[a][b] = (f32x4){0.f, 0.f, 0.f, 0.f};

    for (int k0 = 0; k0 < K; k0 += 64) {
#pragma unroll
        for (int ss = 0; ss < 4; ++ss) {
            gl2lds16(ga + (size_t)ss * 8 * lda + k0, la + ss * 8 * 64);
            gl2lds16(gb + (size_t)ss * 8 * ldb + k0, lb + ss * 8 * 64);
        }
        __syncthreads();

#pragma unroll
        for (int kk = 0; kk < 2; ++kk) {
            bf16x8 af[4], bfr[4];
            const int ca = ((kk * 4 + fq) ^ sw) << 3;
#pragma unroll
            for (int tt = 0; tt < 4; ++tt) {
                af[tt]  = *(const bf16x8*)(&As[(wi + tt * 16 + fr) * 64 + ca]);
                bfr[tt] = *(const bf16x8*)(&Bs[(wj + tt * 16 + fr) * 64 + ca]);
            }
#pragma unroll
            for (int a = 0; a < 4; ++a)
#pragma unroll
                for (int b = 0; b < 4; ++b)
                    acc[a][b] = __builtin_amdgcn_mfma_f32_16x16x32_bf16(
                        af[a], bfr[b], acc[a][b], 0, 0, 0);
        }
        __syncthreads();
    }

    // epilogue: C/D map row = fq*4 + r, col = fr per 16x16 tile
    const int orow = fq * 4;

    float rjv[4];
    if (EPI == 3) {
        const float* ri = rsum + (size_t)bz * N_PIX;
#pragma unroll
        for (int b = 0; b < 4; ++b)
            rjv[b] = ri[j0 + wj + b * 16 + fr];
    }

    float rpart[4][4];
    if (EPI == 1) {
#pragma unroll
        for (int a = 0; a < 4; ++a)
#pragma unroll
            for (int r = 0; r < 4; ++r)
                rpart[a][r] = 0.f;
    }

#pragma unroll
    for (int a = 0; a < 4; ++a) {
        int ibx = i0 + wi + a * 16 + orow;
#pragma unroll
        for (int b = 0; b < 4; ++b) {
            int j = j0 + wj + b * 16 + fr;
            float bj = (BIAS_MODE == 2) ? bias[j] : 0.f;
#pragma unroll
            for (int r = 0; r < 4; ++r) {
                int i = ibx + r;
                float v = acc[a][b][r] * scale;
                if (EPI == 3) v *= rjv[b];
                if (BIAS_MODE == 1) v += bias[i];
                if (BIAS_MODE == 2) v += bj;
                if (EPI == 1) { v = __expf(v); rpart[a][r] += v; }
                if (OUT_BF16)
                    D16[(size_t)i * ldd + j] = __float2bfloat16(v);
                else
                    D32[(size_t)i * ldd + j] = v;
            }
        }
    }

    if (EPI == 1) {
#pragma unroll
        for (int m = 1; m < 16; m <<= 1)
#pragma unroll
            for (int a = 0; a < 4; ++a)
#pragma unroll
                for (int r = 0; r < 4; ++r)
                    rpart[a][r] += __shfl_xor(rpart[a][r], m);
        float* rsl = (float*)As;
        if (fr == 0) {
#pragma unroll
            for (int a = 0; a < 4; ++a)
#pragma unroll
                for (int r = 0; r < 4; ++r)
                    rsl[wave * 64 + a * 16 + orow + r] = rpart[a][r];
        }
        __syncthreads();
        if (tid < 128) {
            int half = tid >> 6, rr = tid & 63;
            float sm = rsl[(half * 2) * 64 + rr] + rsl[(half * 2 + 1) * 64 + rr];
            rsum[((size_t)jb * N_BATCH + bz) * N_PIX + i0 + tid] = sm;
        }
    }
}

// ---------------------------------------------------------------------------
// Merged Q/K/V projection: 3 slots x 8 batches x 72 tiles = 1728 blocks.
// s = lin%24: bz = s&7 (XCD = lin%8), mat = s>>3 (0:Q 1:K 2:V).
// All three: D[n,o] = sum_c X[n,c]*W[o,c] + b[o], D -> QKV + mat*8*N*C.
// ---------------------------------------------------------------------------
__global__ __launch_bounds__(256)
void proj_qkv(const __hip_bfloat16* __restrict__ Xl,
              const __hip_bfloat16* __restrict__ Xg,
              const __hip_bfloat16* __restrict__ wgt,
              const float* __restrict__ bq, const float* __restrict__ bk,
              const float* __restrict__ bv,
              __hip_bfloat16* __restrict__ QKV)
{
    __shared__ __hip_bfloat16 As[128 * 64];
    __shared__ __hip_bfloat16 Bs[128 * 64];

    const int lin = blockIdx.x;
    const int s   = lin % 24;
    const int bz  = s & 7;
    const int mat = s >> 3;
    const int t   = lin / 24;
    const int j0  = (t & 3) * 128;
    const int i0  = (t >> 2) * 128;

    const __hip_bfloat16* Ab = ((mat == 0) ? Xl : Xg) + (size_t)bz * N_PIX * C_DIM;
    const __hip_bfloat16* Bb = wgt + (size_t)mat * C_DIM * C_DIM;
    const float* bias = (mat == 0) ? bq : (mat == 1) ? bk : bv;
    __hip_bfloat16* D = QKV + ((size_t)mat * N_BATCH + bz) * N_PIX * C_DIM;

    const int tid  = threadIdx.x;
    const int lane = tid & 63;
    const int wave = tid >> 6;

    const int lrow = lane >> 3;
    const int lcs  = (lane & 7) ^ lrow;
    const __hip_bfloat16* ga = Ab + (size_t)(i0 + wave * 32 + lrow) * C_DIM + lcs * 8;
    const __hip_bfloat16* gb = Bb + (size_t)(j0 + wave * 32 + lrow) * C_DIM + lcs * 8;
    __hip_bfloat16* la = As + wave * 32 * 64;
    __hip_bfloat16* lb = Bs + wave * 32 * 64;

    const int fr = lane & 15;
    const int fq = lane >> 4;
    const int sw = fr & 7;
    const int wi = (wave >> 1) * 64;
    const int wj = (wave & 1) * 64;

    f32x4 acc[4][4];
#pragma unroll
    for (int a = 0; a < 4; ++a)
#pragma unroll
        for (int b = 0; b < 4; ++b)
            acc[a][b] = (f32x4){0.f, 0.f, 0.f, 0.f};

    for (int k0 = 0; k0 < C_DIM; k0 += 64) {
#pragma unroll
        for (int ss = 0; ss < 4; ++ss) {
            gl2lds16(ga + (size_t)ss * 8 * C_DIM + k0, la + ss * 8 * 64);
            gl2lds16(gb + (size_t)ss * 8 * C_DIM + k0, lb + ss * 8 * 64);
        }
        __syncthreads();

#pragma unroll
        for (int kk = 0; kk < 2; ++kk) {
            bf16x8 af[4], bfr[4];
            const int ca = ((kk * 4 + fq) ^ sw) << 3;
#pragma unroll
            for (int tt = 0; tt < 4; ++tt) {
                af[tt]  = *(const bf16x8*)(&As[(wi + tt * 16 + fr) * 64 + ca]);
                bfr[tt] = *(const bf16x8*)(&Bs[(wj + tt * 16 + fr) * 64 + ca]);
            }
#pragma unroll
            for (int a = 0; a < 4; ++a)
#pragma unroll
                for (int b = 0; b < 4; ++b)
                    acc[a][b] = __builtin_amdgcn_mfma_f32_16x16x32_bf16(
                        af[a], bfr[b], acc[a][b], 0, 0, 0);
        }
        __syncthreads();
    }

    const int orow = fq * 4;
#pragma unroll
    for (int a = 0; a < 4; ++a) {
        int ibx = i0 + wi + a * 16 + orow;
#pragma unroll
        for (int b = 0; b < 4; ++b) {
            int j = j0 + wj + b * 16 + fr;
            float bj = bias[j];
#pragma unroll
            for (int r = 0; r < 4; ++r)
                D[(size_t)(ibx + r) * C_DIM + j] = __float2bfloat16(acc[a][b][r] + bj);
        }
    }
}

// ---------------------------------------------------------------------------
__global__ __launch_bounds__(256)
void reduce_rinv(const float* __restrict__ rp, float* __restrict__ rinv)
{
    int idx = blockIdx.x * 256 + threadIdx.x;
    float s = 0.f;
#pragma unroll
    for (int jb = 0; jb < NJB; ++jb)
        s += rp[(size_t)jb * N_BATCH * N_PIX + idx];
    rinv[idx] = 1.f / s;
}

// ---------------------------------------------------------------------------
// Transpose+cast both inputs: z<8 -> locx->Xl, z>=8 -> glox->Xg. 64x64 tiles.
// ---------------------------------------------------------------------------
__global__ __launch_bounds__(256)
void transpose_cast(const float* __restrict__ locx, const float* __restrict__ glox,
                    __hip_bfloat16* __restrict__ Xl, __hip_bfloat16* __restrict__ Xg)
{
    __shared__ float t[64 * 65];
    const int n0 = blockIdx.x * 64;
    const int c0 = blockIdx.y * 64;
    const int z  = blockIdx.z;
    const size_t b = z & 7;
    const float* Xb = ((z < 8) ? locx : glox) + b * (size_t)C_DIM * N_PIX;
    __hip_bfloat16* Xt = (z < 8) ? Xl : Xg;
    const int tid = threadIdx.x;

    const int n_l = tid & 63;
    const int c_b = tid >> 6;
#pragma unroll
    for (int s = 0; s < 16; ++s) {
        int c_l = c_b + s * 4;
        t[c_l * 65 + n_l] = Xb[(size_t)(c0 + c_l) * N_PIX + n0 + n_l];
    }
    __syncthreads();

    const int cc = (tid & 7) * 8;
    const int nb = tid >> 3;
#pragma unroll
    for (int it = 0; it < 2; ++it) {
        int n2 = nb + it * 32;
        union { __hip_bfloat16 h[8]; int4 v; } u;
#pragma unroll
        for (int w = 0; w < 8; ++w)
            u.h[w] = __float2bfloat16(t[(cc + w) * 65 + n2]);
        *(int4*)(&Xt[(b * N_PIX + n0 + n2) * C_DIM + c0 + cc]) = u.v;
    }
}

// ---------------------------------------------------------------------------
__global__ __launch_bounds__(256)
void cast_w4(const float* __restrict__ s0, const float* __restrict__ s1,
             const float* __restrict__ s2, const float* __restrict__ s3,
             __hip_bfloat16* __restrict__ dst)
{
    const float* srcs[4] = {s0, s1, s2, s3};
    const int w = blockIdx.y;
    const int i = (blockIdx.x * 256 + threadIdx.x) * 4;
    float4 f = *(const float4*)(srcs[w] + i);
    union { __hip_bfloat16 h[4]; s16x4 q; } t;
    t.h[0] = __float2bfloat16(f.x);
    t.h[1] = __float2bfloat16(f.y);
    t.h[2] = __float2bfloat16(f.z);
    t.h[3] = __float2bfloat16(f.w);
    *(s16x4*)(dst + (size_t)w * C_DIM * C_DIM + i) = t.q;
}

// ---------------------------------------------------------------------------
extern "C" void kernel_launch(void* const* d_in, const int* in_sizes, int n_in,
                              void* d_out, int out_size, void* d_ws, size_t ws_size,
                              hipStream_t stream)
{
    const float* locx = (const float*)d_in[0];
    const float* glox = (const float*)d_in[1];
    const float* Wq = (const float*)d_in[2];
    const float* bq = (const float*)d_in[3];
    const float* Wk = (const float*)d_in[4];
    const float* bk = (const float*)d_in[5];
    const float* Wv = (const float*)d_in[6];
    const float* bv = (const float*)d_in[7];
    const float* Wo = (const float*)d_in[8];
    const float* bo = (const float*)d_in[9];
    float* out = (float*)d_out;

    const int C = C_DIM, N = N_PIX;
    const size_t WB   = (size_t)C * C * 2;
    const size_t szX  = (size_t)N_BATCH * N * C * 2;   // 18.87 MB
    const size_t szP1 = (size_t)N * N * 2;
    const size_t szRP = (size_t)NJB * N_BATCH * N * 4;
    const size_t szRI = (size_t)N_BATCH * N * 4;

    const size_t fixed = 4 * WB + 6 * szX + szRP + szRI; // wgt + Xl,Xg,QKV(3),Vp
    bool full = (ws_size >= fixed + 8 * szP1 + 4096);

    char* ws = (char*)d_ws;
    size_t off = 0;
    auto alloc = [&](size_t bytes) {
        char* p = ws + off;
        off += (bytes + 255) & ~(size_t)255;
        return p;
    };
    __hip_bfloat16* wgt = (__hip_bfloat16*)alloc(4 * WB);
    __hip_bfloat16* Xl  = (__hip_bfloat16*)alloc(szX);
    __hip_bfloat16* Xg  = (__hip_bfloat16*)alloc(szX);
    __hip_bfloat16* QKV = (__hip_bfloat16*)alloc(3 * szX);
    __hip_bfloat16* Vp  = (__hip_bfloat16*)alloc(szX);
    float*          rp   = (float*)alloc(szRP);
    float*          rinv = (float*)alloc(szRI);
    __hip_bfloat16* Pu  = (__hip_bfloat16*)alloc(full ? 8 * szP1 : szP1);

    __hip_bfloat16* Qt = QKV;
    __hip_bfloat16* Kt = QKV + (size_t)N_BATCH * N * C;
    __hip_bfloat16* Vt = QKV + 2 * (size_t)N_BATCH * N * C;
    __hip_bfloat16* wo_b = wgt + 3 * (size_t)C * C;

    const dim3 blk(256);
    const long sPr = (long)N * C;   // [N,C] batch stride
    const long sCN = (long)C * N;   // [C,N] batch stride

    cast_w4<<<dim3(C * C / 1024, 4), blk, 0, stream>>>(Wq, Wk, Wv, Wo, wgt);
    transpose_cast<<<dim3(N / 64, C / 64, 16), blk, 0, stream>>>(locx, glox, Xl, Xg);

    // Qt/Kt/Vt[n,o] = sum_c X[n,c]*W[o,c] + b[o]
    proj_qkv<<<dim3(24 * 72), blk, 0, stream>>>(Xl, Xg, wgt, bq, bk, bv, QKV);

    if (full) {
        // Pu = exp(SCALE * Qt Kt^T), rowsum partials -> rp
        gemm_bt<1, 0, 1, 18, 8, 0, 0><<<dim3(18 * 18 * 8), blk, 0, stream>>>(
            Qt, Kt, Pu, nullptr, rp,
            ATT_SCALE, C, C, C, N, sPr, sPr, (long)N * N);
        // V'[o,m] = sum_c Wo[o,c]*Vt[m,c]   (layout [C,N])
        gemm_bt<1, 0, 0, 18, 8, 1, 4><<<dim3(4 * 18 * 8), blk, 0, stream>>>(
            wo_b, Vt, Vp, nullptr, nullptr,
            1.f, C, C, C, N, 0, sPr, sCN);
        reduce_rinv<<<dim3(8 * N / 256), blk, 0, stream>>>(rp, rinv);
        // out[o,n] = rinv[n] * sum_m V'[o,m]*Pu[n,m] + bo[o]   (fp32)
        gemm_bt<0, 1, 3, 18, 8, 1, 4><<<dim3(4 * 18 * 8), blk, 0, stream>>>(
            Vp, Pu, out, bo, rinv,
            1.f, N, N, N, N, sCN, (long)N * N, sCN);
    } else {
        // V' first (needs only Vt)
        gemm_bt<1, 0, 0, 18, 8, 1, 4><<<dim3(4 * 18 * 8), blk, 0, stream>>>(
            wo_b, Vt, Vp, nullptr, nullptr,
            1.f, C, C, C, N, 0, sPr, sCN);
        for (int r = 0; r < N_BATCH; ++r) {
            gemm_bt<1, 0, 1, 18, 1, 0, 0><<<dim3(18 * 18), blk, 0, stream>>>(
                Qt + (size_t)r * sPr, Kt + (size_t)r * sPr, Pu, nullptr,
                rp + (size_t)r * N,
                ATT_SCALE, C, C, C, N, 0, 0, 0);
            reduce_rinv<<<dim3(N / 256), blk, 0, stream>>>(
                rp + (size_t)r * N, rinv + (size_t)r * N);
            gemm_bt<0, 1, 3, 18, 1, 1, 4><<<dim3(4 * 18), blk, 0, stream>>>(
                Vp + (size_t)r * sCN, Pu, out + (size_t)r * sCN, bo,
                rinv + (size_t)r * N,
                1.f, N, N, N, N, 0, 0, 0);
        }
    }
}

// Round 6
// 312.908 us; speedup vs baseline: 1.6446x; 1.0860x over previous
//
#include <hip/hip_runtime.h>
#include <hip/hip_bf16.h>

typedef __attribute__((ext_vector_type(4))) float f32x4;
typedef __attribute__((ext_vector_type(8))) short bf16x8;
typedef __attribute__((ext_vector_type(4))) short s16x4;

#define C_DIM 512
#define N_PIX 2304
#define N_BATCH 8
#define ATT_SCALE 0.04419417382415922f
#define NJB 18                      // N_PIX / 128

typedef __attribute__((address_space(3))) unsigned int lds_u32;
typedef const __attribute__((address_space(1))) unsigned int glob_u32;

__device__ __forceinline__ void gl2lds16(const __hip_bfloat16* g, __hip_bfloat16* l)
{
    __builtin_amdgcn_global_load_lds((glob_u32*)g, (lds_u32*)l, 16, 0, 0);
}

// ---------------------------------------------------------------------------
// Merged S + V' dispatch. 1-D grid, NS batches (lin%NS -> XCD pin), t=lin/NS:
//   t < 324 : S-block   : Pu[n,m] = exp(SC * sum_o Qt[n,o]Kt[m,o]), rp partials
//   t >= 324: V'-block  : Vp[o,m] = sum_c Wo[o,c]*Vt[m,c]
// Both are K=512 gemm_bt's; 128x128 tile, BK=64, global_load_lds + XOR swizzle.
// rp layout: rp[(jb*8 + bz)*N + i].
// ---------------------------------------------------------------------------
template<int NS>
__global__ __launch_bounds__(256)
void s_vp(const __hip_bfloat16* __restrict__ Qt, const __hip_bfloat16* __restrict__ Kt,
          __hip_bfloat16* __restrict__ Pu, float* __restrict__ rp,
          const __hip_bfloat16* __restrict__ wo, const __hip_bfloat16* __restrict__ Vt,
          __hip_bfloat16* __restrict__ Vp, int bz_off, long sPu)
{
    __shared__ __hip_bfloat16 As[128 * 64];
    __shared__ __hip_bfloat16 Bs[128 * 64];

    const int lin = blockIdx.x;
    const int bz  = lin % NS + bz_off;
    const int t   = lin / NS;
    const bool is_s = (t < 324);

    int ib, jb;
    const __hip_bfloat16 *A, *B;
    __hip_bfloat16* D;
    float scale;
    const long sQ = (long)N_PIX * C_DIM;
    if (is_s) {
        ib = t / 18; jb = t % 18;
        A = Qt + (size_t)bz * sQ;
        B = Kt + (size_t)bz * sQ;
        D = Pu + (size_t)bz * (size_t)sPu;
        scale = ATT_SCALE;
    } else {
        int u = t - 324;          // 0..71
        ib = u / 18; jb = u % 18;
        A = wo;
        B = Vt + (size_t)bz * sQ;
        D = Vp + (size_t)bz * sQ;
        scale = 1.f;
    }
    const int i0 = ib * 128;
    const int j0 = jb * 128;

    const int tid  = threadIdx.x;
    const int lane = tid & 63;
    const int wave = tid >> 6;

    const int lrow = lane >> 3;
    const int lcs  = (lane & 7) ^ lrow;
    const __hip_bfloat16* ga = A + (size_t)(i0 + wave * 32 + lrow) * C_DIM + lcs * 8;
    const __hip_bfloat16* gb = B + (size_t)(j0 + wave * 32 + lrow) * C_DIM + lcs * 8;
    __hip_bfloat16* la = As + wave * 32 * 64;
    __hip_bfloat16* lb = Bs + wave * 32 * 64;

    const int fr = lane & 15;
    const int fq = lane >> 4;
    const int sw = fr & 7;
    const int wi = (wave >> 1) * 64;
    const int wj = (wave & 1) * 64;

    f32x4 acc[4][4];
#pragma unroll
    for (int a = 0; a < 4; ++a)
#pragma unroll
        for (int b = 0; b < 4; ++b)
            acc[a][b] = (f32x4){0.f, 0.f, 0.f, 0.f};

    for (int k0 = 0; k0 < C_DIM; k0 += 64) {
#pragma unroll
        for (int ss = 0; ss < 4; ++ss) {
            gl2lds16(ga + (size_t)ss * 8 * C_DIM + k0, la + ss * 8 * 64);
            gl2lds16(gb + (size_t)ss * 8 * C_DIM + k0, lb + ss * 8 * 64);
        }
        __syncthreads();

#pragma unroll
        for (int kk = 0; kk < 2; ++kk) {
            bf16x8 af[4], bfr[4];
            const int ca = ((kk * 4 + fq) ^ sw) << 3;
#pragma unroll
            for (int tt = 0; tt < 4; ++tt) {
                af[tt]  = *(const bf16x8*)(&As[(wi + tt * 16 + fr) * 64 + ca]);
                bfr[tt] = *(const bf16x8*)(&Bs[(wj + tt * 16 + fr) * 64 + ca]);
            }
#pragma unroll
            for (int a = 0; a < 4; ++a)
#pragma unroll
                for (int b = 0; b < 4; ++b)
                    acc[a][b] = __builtin_amdgcn_mfma_f32_16x16x32_bf16(
                        af[a], bfr[b], acc[a][b], 0, 0, 0);
        }
        __syncthreads();
    }

    const int orow = fq * 4;

    if (is_s) {
        float rpart[4][4];
#pragma unroll
        for (int a = 0; a < 4; ++a)
#pragma unroll
            for (int r = 0; r < 4; ++r)
                rpart[a][r] = 0.f;
#pragma unroll
        for (int a = 0; a < 4; ++a) {
            int ibx = i0 + wi + a * 16 + orow;
#pragma unroll
            for (int b = 0; b < 4; ++b) {
                int j = j0 + wj + b * 16 + fr;
#pragma unroll
                for (int r = 0; r < 4; ++r) {
                    float v = __expf(acc[a][b][r] * scale);
                    rpart[a][r] += v;
                    D[(size_t)(ibx + r) * N_PIX + j] = __float2bfloat16(v);
                }
            }
        }
#pragma unroll
        for (int m = 1; m < 16; m <<= 1)
#pragma unroll
            for (int a = 0; a < 4; ++a)
#pragma unroll
                for (int r = 0; r < 4; ++r)
                    rpart[a][r] += __shfl_xor(rpart[a][r], m);
        float* rsl = (float*)As;
        if (fr == 0) {
#pragma unroll
            for (int a = 0; a < 4; ++a)
#pragma unroll
                for (int r = 0; r < 4; ++r)
                    rsl[wave * 64 + a * 16 + orow + r] = rpart[a][r];
        }
        __syncthreads();
        if (tid < 128) {
            int half = tid >> 6, rr = tid & 63;
            float sm = rsl[(half * 2) * 64 + rr] + rsl[(half * 2 + 1) * 64 + rr];
            rp[((size_t)jb * N_BATCH + bz) * N_PIX + i0 + tid] = sm;
        }
    } else {
#pragma unroll
        for (int a = 0; a < 4; ++a) {
            int ibx = i0 + wi + a * 16 + orow;
#pragma unroll
            for (int b = 0; b < 4; ++b) {
                int j = j0 + wj + b * 16 + fr;
#pragma unroll
                for (int r = 0; r < 4; ++r)
                    D[(size_t)(ibx + r) * N_PIX + j] = __float2bfloat16(acc[a][b][r]);
            }
        }
    }
}

// ---------------------------------------------------------------------------
// PV + output: out[o,n] = rinv[n] * sum_m Vp[o,m]*Pu[n,m] + bo[o]  (fp32)
// 64x128 tile (i=o 8 tiles, j=n 18 tiles), K=N=2304. Grid NS*144, i-fast.
// rinv computed in-epilogue from rp partials (sum of 18).
// ---------------------------------------------------------------------------
template<int NS>
__global__ __launch_bounds__(256)
void pv_out(const __hip_bfloat16* __restrict__ Vp, const __hip_bfloat16* __restrict__ Pu,
            float* __restrict__ out, const float* __restrict__ bo,
            const float* __restrict__ rp, int bz_off, long sPu)
{
    __shared__ __hip_bfloat16 As[64 * 64];
    __shared__ __hip_bfloat16 Bs[128 * 64];

    const int lin = blockIdx.x;
    const int bz  = lin % NS + bz_off;
    const int t   = lin / NS;
    const int ib  = t % 8;       // i-fast: consecutive blocks share Pu j-tile
    const int jb  = t / 8;
    const int i0  = ib * 64;
    const int j0  = jb * 128;

    const long sCN = (long)C_DIM * N_PIX;
    const __hip_bfloat16* A = Vp + (size_t)bz * sCN;   // [C,N] lda=N
    const __hip_bfloat16* B = Pu + (size_t)bz * (size_t)sPu; // [N,N] ldb=N
    float* D = out + (size_t)bz * sCN;

    const int tid  = threadIdx.x;
    const int lane = tid & 63;
    const int wave = tid >> 6;

    const int lrow = lane >> 3;
    const int lcs  = (lane & 7) ^ lrow;
    const __hip_bfloat16* ga = A + (size_t)(i0 + wave * 16 + lrow) * N_PIX + lcs * 8;
    const __hip_bfloat16* gb = B + (size_t)(j0 + wave * 32 + lrow) * N_PIX + lcs * 8;
    __hip_bfloat16* la = As + wave * 16 * 64;
    __hip_bfloat16* lb = Bs + wave * 32 * 64;

    const int fr = lane & 15;
    const int fq = lane >> 4;
    const int sw = fr & 7;
    const int wi = (wave >> 1) * 32;
    const int wj = (wave & 1) * 64;

    f32x4 acc[2][4];
#pragma unroll
    for (int a = 0; a < 2; ++a)
#pragma unroll
        for (int b = 0; b < 4; ++b)
            acc[a][b] = (f32x4){0.f, 0.f, 0.f, 0.f};

    for (int k0 = 0; k0 < N_PIX; k0 += 64) {
#pragma unroll
        for (int ss = 0; ss < 2; ++ss)
            gl2lds16(ga + (size_t)ss * 8 * N_PIX + k0, la + ss * 8 * 64);
#pragma unroll
        for (int ss = 0; ss < 4; ++ss)
            gl2lds16(gb + (size_t)ss * 8 * N_PIX + k0, lb + ss * 8 * 64);
        __syncthreads();

#pragma unroll
        for (int kk = 0; kk < 2; ++kk) {
            bf16x8 af[2], bfr[4];
            const int ca = ((kk * 4 + fq) ^ sw) << 3;
#pragma unroll
            for (int tt = 0; tt < 2; ++tt)
                af[tt]  = *(const bf16x8*)(&As[(wi + tt * 16 + fr) * 64 + ca]);
#pragma unroll
            for (int tt = 0; tt < 4; ++tt)
                bfr[tt] = *(const bf16x8*)(&Bs[(wj + tt * 16 + fr) * 64 + ca]);
#pragma unroll
            for (int a = 0; a < 2; ++a)
#pragma unroll
                for (int b = 0; b < 4; ++b)
                    acc[a][b] = __builtin_amdgcn_mfma_f32_16x16x32_bf16(
                        af[a], bfr[b], acc[a][b], 0, 0, 0);
        }
        __syncthreads();
    }

    // rinv per output column (4 cols/thread), from 18 rp partials each
    const int orow = fq * 4;
    float rjv[4];
#pragma unroll
    for (int b = 0; b < 4; ++b) {
        int j = j0 + wj + b * 16 + fr;
        float s = 0.f;
#pragma unroll
        for (int jj = 0; jj < NJB; ++jj)
            s += rp[((size_t)jj * N_BATCH + bz) * N_PIX + j];
        rjv[b] = 1.f / s;
    }

#pragma unroll
    for (int a = 0; a < 2; ++a) {
        int ibx = i0 + wi + a * 16 + orow;
#pragma unroll
        for (int r = 0; r < 4; ++r) {
            float bi = bo[ibx + r];
#pragma unroll
            for (int b = 0; b < 4; ++b) {
                int j = j0 + wj + b * 16 + fr;
                D[(size_t)(ibx + r) * N_PIX + j] = acc[a][b][r] * rjv[b] + bi;
            }
        }
    }
}

// ---------------------------------------------------------------------------
// Merged Q/K/V projection: 3 mats x 8 batches x 72 tiles = 1728 blocks.
// ---------------------------------------------------------------------------
__global__ __launch_bounds__(256)
void proj_qkv(const __hip_bfloat16* __restrict__ Xl,
              const __hip_bfloat16* __restrict__ Xg,
              const __hip_bfloat16* __restrict__ wgt,
              const float* __restrict__ bq, const float* __restrict__ bk,
              const float* __restrict__ bv,
              __hip_bfloat16* __restrict__ QKV)
{
    __shared__ __hip_bfloat16 As[128 * 64];
    __shared__ __hip_bfloat16 Bs[128 * 64];

    const int lin = blockIdx.x;
    const int s   = lin % 24;
    const int bz  = s & 7;
    const int mat = s >> 3;
    const int t   = lin / 24;
    const int j0  = (t & 3) * 128;
    const int i0  = (t >> 2) * 128;

    const __hip_bfloat16* Ab = ((mat == 0) ? Xl : Xg) + (size_t)bz * N_PIX * C_DIM;
    const __hip_bfloat16* Bb = wgt + (size_t)mat * C_DIM * C_DIM;
    const float* bias = (mat == 0) ? bq : (mat == 1) ? bk : bv;
    __hip_bfloat16* D = QKV + ((size_t)mat * N_BATCH + bz) * N_PIX * C_DIM;

    const int tid  = threadIdx.x;
    const int lane = tid & 63;
    const int wave = tid >> 6;

    const int lrow = lane >> 3;
    const int lcs  = (lane & 7) ^ lrow;
    const __hip_bfloat16* ga = Ab + (size_t)(i0 + wave * 32 + lrow) * C_DIM + lcs * 8;
    const __hip_bfloat16* gb = Bb + (size_t)(j0 + wave * 32 + lrow) * C_DIM + lcs * 8;
    __hip_bfloat16* la = As + wave * 32 * 64;
    __hip_bfloat16* lb = Bs + wave * 32 * 64;

    const int fr = lane & 15;
    const int fq = lane >> 4;
    const int sw = fr & 7;
    const int wi = (wave >> 1) * 64;
    const int wj = (wave & 1) * 64;

    f32x4 acc[4][4];
#pragma unroll
    for (int a = 0; a < 4; ++a)
#pragma unroll
        for (int b = 0; b < 4; ++b)
            acc[a][b] = (f32x4){0.f, 0.f, 0.f, 0.f};

    for (int k0 = 0; k0 < C_DIM; k0 += 64) {
#pragma unroll
        for (int ss = 0; ss < 4; ++ss) {
            gl2lds16(ga + (size_t)ss * 8 * C_DIM + k0, la + ss * 8 * 64);
            gl2lds16(gb + (size_t)ss * 8 * C_DIM + k0, lb + ss * 8 * 64);
        }
        __syncthreads();

#pragma unroll
        for (int kk = 0; kk < 2; ++kk) {
            bf16x8 af[4], bfr[4];
            const int ca = ((kk * 4 + fq) ^ sw) << 3;
#pragma unroll
            for (int tt = 0; tt < 4; ++tt) {
                af[tt]  = *(const bf16x8*)(&As[(wi + tt * 16 + fr) * 64 + ca]);
                bfr[tt] = *(const bf16x8*)(&Bs[(wj + tt * 16 + fr) * 64 + ca]);
            }
#pragma unroll
            for (int a = 0; a < 4; ++a)
#pragma unroll
                for (int b = 0; b < 4; ++b)
                    acc[a][b] = __builtin_amdgcn_mfma_f32_16x16x32_bf16(
                        af[a], bfr[b], acc[a][b], 0, 0, 0);
        }
        __syncthreads();
    }

    const int orow = fq * 4;
#pragma unroll
    for (int a = 0; a < 4; ++a) {
        int ibx = i0 + wi + a * 16 + orow;
#pragma unroll
        for (int b = 0; b < 4; ++b) {
            int j = j0 + wj + b * 16 + fr;
            float bj = bias[j];
#pragma unroll
            for (int r = 0; r < 4; ++r)
                D[(size_t)(ibx + r) * C_DIM + j] = __float2bfloat16(acc[a][b][r] + bj);
        }
    }
}

// ---------------------------------------------------------------------------
// prep: blocks [0,4608) transpose+cast inputs (z<8 locx->Xl else glox->Xg);
//       blocks [4608,5632) cast the 4 weight mats to contiguous bf16.
// ---------------------------------------------------------------------------
__global__ __launch_bounds__(256)
void prep(const float* __restrict__ locx, const float* __restrict__ glox,
          __hip_bfloat16* __restrict__ Xl, __hip_bfloat16* __restrict__ Xg,
          const float* __restrict__ w0, const float* __restrict__ w1,
          const float* __restrict__ w2, const float* __restrict__ w3,
          __hip_bfloat16* __restrict__ wgt)
{
    const int lin = blockIdx.x;
    const int tid = threadIdx.x;

    if (lin < 4608) {
        __shared__ float t[64 * 65];
        const int z  = lin & 15;
        const int t2 = lin >> 4;
        const int c0 = (t2 & 7) * 64;
        const int n0 = (t2 >> 3) * 64;
        const size_t b = z & 7;
        const float* Xb = ((z < 8) ? locx : glox) + b * (size_t)C_DIM * N_PIX;
        __hip_bfloat16* Xt = (z < 8) ? Xl : Xg;

        const int n_l = tid & 63;
        const int c_b = tid >> 6;
#pragma unroll
        for (int s = 0; s < 16; ++s) {
            int c_l = c_b + s * 4;
            t[c_l * 65 + n_l] = Xb[(size_t)(c0 + c_l) * N_PIX + n0 + n_l];
        }
        __syncthreads();

        const int cc = (tid & 7) * 8;
        const int nb = tid >> 3;
#pragma unroll
        for (int it = 0; it < 2; ++it) {
            int n2 = nb + it * 32;
            union { __hip_bfloat16 h[8]; int4 v; } u;
#pragma unroll
            for (int w = 0; w < 8; ++w)
                u.h[w] = __float2bfloat16(t[(cc + w) * 65 + n2]);
            *(int4*)(&Xt[(b * N_PIX + n0 + n2) * C_DIM + c0 + cc]) = u.v;
        }
    } else {
        const int idx = lin - 4608;          // 0..1023
        const int w   = idx >> 8;            // 0..3
        const float* srcs[4] = {w0, w1, w2, w3};
        const int i = ((idx & 255) * 256 + tid) * 4;
        float4 f = *(const float4*)(srcs[w] + i);
        union { __hip_bfloat16 h[4]; s16x4 q; } u;
        u.h[0] = __float2bfloat16(f.x);
        u.h[1] = __float2bfloat16(f.y);
        u.h[2] = __float2bfloat16(f.z);
        u.h[3] = __float2bfloat16(f.w);
        *(s16x4*)(wgt + (size_t)w * C_DIM * C_DIM + i) = u.q;
    }
}

// ---------------------------------------------------------------------------
extern "C" void kernel_launch(void* const* d_in, const int* in_sizes, int n_in,
                              void* d_out, int out_size, void* d_ws, size_t ws_size,
                              hipStream_t stream)
{
    const float* locx = (const float*)d_in[0];
    const float* glox = (const float*)d_in[1];
    const float* Wq = (const float*)d_in[2];
    const float* bq = (const float*)d_in[3];
    const float* Wk = (const float*)d_in[4];
    const float* bk = (const float*)d_in[5];
    const float* Wv = (const float*)d_in[6];
    const float* bv = (const float*)d_in[7];
    const float* Wo = (const float*)d_in[8];
    const float* bo = (const float*)d_in[9];
    float* out = (float*)d_out;

    const int C = C_DIM, N = N_PIX;
    const size_t WB   = (size_t)C * C * 2;
    const size_t szX  = (size_t)N_BATCH * N * C * 2;   // 18.87 MB
    const size_t szP1 = (size_t)N * N * 2;
    const size_t szRP = (size_t)NJB * N_BATCH * N * 4;

    const size_t fixed = 4 * WB + 6 * szX + szRP;      // wgt + Xl,Xg,QKV(3),Vp + rp
    bool full = (ws_size >= fixed + 8 * szP1 + 4096);

    char* ws = (char*)d_ws;
    size_t off = 0;
    auto alloc = [&](size_t bytes) {
        char* p = ws + off;
        off += (bytes + 255) & ~(size_t)255;
        return p;
    };
    __hip_bfloat16* wgt = (__hip_bfloat16*)alloc(4 * WB);
    __hip_bfloat16* Xl  = (__hip_bfloat16*)alloc(szX);
    __hip_bfloat16* Xg  = (__hip_bfloat16*)alloc(szX);
    __hip_bfloat16* QKV = (__hip_bfloat16*)alloc(3 * szX);
    __hip_bfloat16* Vp  = (__hip_bfloat16*)alloc(szX);
    float*          rp  = (float*)alloc(szRP);
    __hip_bfloat16* Pu  = (__hip_bfloat16*)alloc(full ? 8 * szP1 : szP1);

    __hip_bfloat16* Qt = QKV;
    __hip_bfloat16* Kt = QKV + (size_t)N_BATCH * N * C;
    __hip_bfloat16* Vt = QKV + 2 * (size_t)N_BATCH * N * C;
    __hip_bfloat16* wo_b = wgt + 3 * (size_t)C * C;

    const dim3 blk(256);

    prep<<<dim3(5632), blk, 0, stream>>>(locx, glox, Xl, Xg, Wq, Wk, Wv, Wo, wgt);
    proj_qkv<<<dim3(24 * 72), blk, 0, stream>>>(Xl, Xg, wgt, bq, bk, bv, QKV);

    if (full) {
        s_vp<8><<<dim3(8 * 396), blk, 0, stream>>>(
            Qt, Kt, Pu, rp, wo_b, Vt, Vp, 0, (long)N * N);
        pv_out<8><<<dim3(8 * 144), blk, 0, stream>>>(
            Vp, Pu, out, bo, rp, 0, (long)N * N);
    } else {
        for (int r = 0; r < N_BATCH; ++r) {
            s_vp<1><<<dim3(396), blk, 0, stream>>>(
                Qt, Kt, Pu, rp, wo_b, Vt, Vp, r, 0);
            pv_out<1><<<dim3(144), blk, 0, stream>>>(
                Vp, Pu, out, bo, rp, r, 0);
        }
    }
}